// Round 6
// baseline (6270.475 us; speedup 1.0000x reference)
//
#include <hip/hip_runtime.h>
#include <hip/hip_bf16.h>

// Problem constants
#define B_    64
#define T_    512
#define I_    256
#define H_    1024
#define KTOT  1280          // I_ + H_
#define KSTEPS 40           // KTOT / 32
#define NWG   64            // recurrence workgroups (each owns NJ h-cols)
#define NJ    16            // h-columns per WG -> 64 gate columns (4 tiles: i,f,g,o)
#define WPK_U4_PER_WG (4 * KSTEPS * 64)   // 10240 uint4 per WG slab (160KB source)

typedef __bf16 bf16x8 __attribute__((ext_vector_type(8)));
typedef float  f32x4  __attribute__((ext_vector_type(4)));

__device__ __forceinline__ unsigned short f2bf(float f) {
  unsigned u = __builtin_bit_cast(unsigned, f);
  u += 0x7FFFu + ((u >> 16) & 1u);       // round-to-nearest-even
  return (unsigned short)(u >> 16);
}
__device__ __forceinline__ float sigm(float x) { return 1.0f / (1.0f + __expf(-x)); }
__device__ __forceinline__ float tanh_fast(float x) {
  float ax = fabsf(x);
  float e  = __expf(-2.0f * ax);          // in (0,1], no overflow
  float t  = (1.0f - e) / (1.0f + e);
  return x < 0.0f ? -t : t;
}

// ---------------- K0: x [B,T,I] f32 -> xb [T,B,I] bf16 ----------------
__global__ void k_pack_x(const float* __restrict__ x, unsigned short* __restrict__ xb) {
  int idx = blockIdx.x * blockDim.x + threadIdx.x;   // over B*T*I/8 = 1,048,576
  int ic = idx & 31;             // I/8 = 32
  int t  = (idx >> 5) & 511;     // T = 512
  int b  = idx >> 14;            // B = 64
  const float* src = x + ((size_t)b * T_ + t) * I_ + ic * 8;
  float4 f0 = *(const float4*)src;
  float4 f1 = *(const float4*)(src + 4);
  unsigned short o[8] = {f2bf(f0.x), f2bf(f0.y), f2bf(f0.z), f2bf(f0.w),
                         f2bf(f1.x), f2bf(f1.y), f2bf(f1.z), f2bf(f1.w)};
  *(uint4*)(xb + ((size_t)t * B_ + b) * I_ + ic * 8) = *(uint4*)o;
}

// ---------------- K1a: pack W_ih|W_hh into per-WG B-fragment layout ----------------
// layout: [w][nt][kk][lane][e]; nt = GATE (0=i,1=f,2=g,3=o), col n = lane&15,
// row r = nt*H + w*16 + n, k = kk*32 + (lane>>4)*8 + e
__global__ void k_pack_w(const float* __restrict__ Wih, const float* __restrict__ Whh,
                         const float* __restrict__ bih, const float* __restrict__ bhh,
                         unsigned short* __restrict__ wpack, float* __restrict__ biasp) {
  int f = blockIdx.x * blockDim.x + threadIdx.x;     // 64*4*40*64 = 655,360
  int l  = f & 63;
  int q  = f >> 6;
  int kk = q % KSTEPS;
  int q2 = q / KSTEPS;
  int nt = q2 & 3;
  int w  = q2 >> 2;
  int n  = l & 15;
  int r  = nt * H_ + w * NJ + n;
  int k0 = kk * 32 + (l >> 4) * 8;
  unsigned short o[8];
#pragma unroll
  for (int e = 0; e < 8; ++e) {
    int k = k0 + e;
    float v = (k < I_) ? Wih[(size_t)r * I_ + k] : Whh[(size_t)r * H_ + (k - I_)];
    o[e] = f2bf(v);
  }
  *(uint4*)(wpack + (size_t)f * 8) = *(uint4*)o;
  if (kk == 0 && (l >> 4) == 0) biasp[w * 64 + nt * 16 + n] = bih[r] + bhh[r];
}

// ---------------- K1b: pack W_fc [I,H] -> fragment layout [kk][nt][lane][e] ----------------
__global__ void k_pack_wfc(const float* __restrict__ Wfc, unsigned short* __restrict__ wfcp) {
  int f = blockIdx.x * blockDim.x + threadIdx.x;     // 32*16*64 = 32768
  int l  = f & 63;
  int nt = (f >> 6) & 15;
  int kk = f >> 10;
  int n  = nt * 16 + (l & 15);
  int k0 = kk * 32 + (l >> 4) * 8;
  unsigned short o[8];
#pragma unroll
  for (int e = 0; e < 8; ++e) o[e] = f2bf(Wfc[(size_t)n * H_ + k0 + e]);
  *(uint4*)(wfcp + (size_t)f * 8) = *(uint4*)o;
}

// ---------------- K1c: h0 -> bf16 hbuf; zero flags ----------------
__global__ void k_init_h(const float* __restrict__ h0, unsigned short* __restrict__ hbuf,
                         unsigned int* __restrict__ flags) {
  int idx = blockIdx.x * blockDim.x + threadIdx.x;   // B*H/8 = 8192
  const float* s = h0 + (size_t)idx * 8;
  unsigned short o[8];
#pragma unroll
  for (int e = 0; e < 8; ++e) o[e] = f2bf(s[e]);
  *(uint4*)(hbuf + (size_t)idx * 8) = *(uint4*)o;
  if (idx < 1024) flags[idx] = 0;
}

// ---------------- K2: persistent LSTM recurrence ----------------
// 64 WGs x 256 threads (4 waves). WG w owns h-cols [w*16, w*16+16); the 4 MFMA
// N-tiles are the 4 GATES for those columns -> i/f/g/o land in the same lane,
// same element: zero-shuffle gate math; 4 independent MFMA chains per wave.
// W_hh-part B-fragments live in LDS (128KB); W_ih-part in registers (xw[4][8]).
// Sync: 256 per-wave flags. Each wave drains its own sc1 h-stores (vmcnt(0)),
// posts its flag, and polls all 256 flags itself (one dwordx4 sc0sc1 per lane).
__global__ void __launch_bounds__(256, 1) k_lstm(
    const unsigned short* __restrict__ xb, const unsigned short* __restrict__ wpack,
    const float* __restrict__ biasp, const float* __restrict__ c0,
    const unsigned short* __restrict__ hbuf, unsigned short* __restrict__ hs,
    unsigned int* __restrict__ flags) {
  __shared__ unsigned short wlds[4 * 32 * 64 * 8];  // 128 KiB: h-part W
  const int w    = blockIdx.x;
  const int tid  = threadIdx.x;
  const int wave = tid >> 6, lane = tid & 63;

  const uint4* wp4 = (const uint4*)wpack + (size_t)w * WPK_U4_PER_WG;

  // x-part W (kk 0..7) into registers: 128 VGPRs
  bf16x8 xw[4][8];
#pragma unroll
  for (int nt = 0; nt < 4; ++nt)
#pragma unroll
    for (int kk = 0; kk < 8; ++kk)
      xw[nt][kk] = __builtin_bit_cast(bf16x8, wp4[(nt * KSTEPS + kk) * 64 + lane]);

  { // h-part W (kk 8..39) into LDS: block-contiguous copy, 32 uint4/thread
    uint4* wl4 = (uint4*)wlds;
    for (int i = tid; i < 8192; i += 256) {
      int blk = i >> 6, within = i & 63;          // blk = nt*32 + kkh
      int nt = blk >> 5, kkh = blk & 31;
      wl4[i] = wp4[(nt * KSTEPS + kkh + 8) * 64 + within];
    }
  }

  const int mA   = wave * 16 + (lane & 15);    // A-fragment row = batch index
  const int kOff = (lane >> 4) * 8;            // A-fragment k offset within 32
  const int mD   = wave * 16 + (lane >> 4) * 4;// D-fragment row base
  const int jst  = w * NJ + (lane & 15);       // owned h-column

  float bias[4];
#pragma unroll
  for (int nt = 0; nt < 4; ++nt) bias[nt] = biasp[w * 64 + nt * 16 + (lane & 15)];
  float creg[4];
#pragma unroll
  for (int e = 0; e < 4; ++e) creg[e] = c0[(size_t)(mD + e) * H_ + jst];

  __syncthreads();   // LDS W ready

  bf16x8 xf[8];      // prefetched x fragments for the NEXT step
  f32x4 xacc[4];
  auto loadX = [&](int t) {
    const unsigned short* xrow = xb + ((size_t)t * B_ + mA) * I_ + kOff;
#pragma unroll
    for (int kk = 0; kk < 8; ++kk) xf[kk] = *(const bf16x8*)(xrow + kk * 32);
  };
  auto computeX = [&]() {   // registers only (xf, xw) -> 32 MFMAs
#pragma unroll
    for (int nt = 0; nt < 4; ++nt) xacc[nt] = f32x4{bias[nt], bias[nt], bias[nt], bias[nt]};
#pragma unroll
    for (int kk = 0; kk < 8; ++kk)
#pragma unroll
      for (int nt = 0; nt < 4; ++nt)
        xacc[nt] = __builtin_amdgcn_mfma_f32_16x16x32_bf16(xf[kk], xw[nt][kk], xacc[nt], 0, 0, 0);
  };
  loadX(0);
  asm volatile("" ::: "memory");
  computeX();

  for (int t = 0; t < T_; ++t) {
    // ---- wait: every wave polls all 256 per-wave flags (1 dwordx4/lane) ----
    if (t > 0) {
      const unsigned target = (unsigned)t;
      const uint4* fp = (const uint4*)flags + lane;   // flags[lane*4 .. lane*4+3]
      int guard = 0;
      for (;;) {
        uint4 v;
        asm volatile("global_load_dwordx4 %0, %1, off sc0 sc1\n\ts_waitcnt vmcnt(0)"
                     : "=&v"(v) : "v"(fp) : "memory");
        if (__all(v.x >= target && v.y >= target && v.z >= target && v.w >= target)) break;
        if (++guard > (1 << 20)) break;   // safety: never hard-hang
      }
      asm volatile("" ::: "memory");   // don't hoist h loads above the poll
    }

    // ---- prefetch 32 h fragments (+ next step's 8 x fragments) ----
    const unsigned short* hprev = (t == 0) ? hbuf : hs + (size_t)(t - 1) * (B_ * H_);
    const unsigned short* hrow = hprev + (size_t)mA * H_ + kOff;
    bf16x8 hf[32];
#pragma unroll
    for (int kk = 0; kk < 32; ++kk)
      hf[kk] = *(const bf16x8*)(hrow + kk * 32);   // plain cached b128 load
    if (t + 1 < T_) loadX(t + 1);
    asm volatile("" ::: "memory");   // loads cannot sink below this point

    // ---- 128 MFMAs: 4 independent chains (one per gate tile) ----
    f32x4 acc[4];
#pragma unroll
    for (int nt = 0; nt < 4; ++nt) acc[nt] = xacc[nt];
#pragma unroll
    for (int kk = 0; kk < 32; ++kk)
#pragma unroll
      for (int nt = 0; nt < 4; ++nt) {
        bf16x8 b = *(const bf16x8*)(wlds + ((size_t)(nt * 32 + kk) * 64 + lane) * 8);
        acc[nt] = __builtin_amdgcn_mfma_f32_16x16x32_bf16(hf[kk], b, acc[nt], 0, 0, 0);
      }

    // ---- gates: i/f/g/o all in-lane (acc[0..3][e]) — zero shuffles ----
    unsigned short hbits[4];
#pragma unroll
    for (int e = 0; e < 4; ++e) {
      float ig = sigm(acc[0][e]), fg = sigm(acc[1][e]);
      float gg = tanh_fast(acc[2][e]), og = sigm(acc[3][e]);
      float cn = fg * creg[e] + ig * gg;
      creg[e] = cn;
      hbits[e] = f2bf(og * tanh_fast(cn));
    }

    // ---- store h_t: pack 4 adjacent cols into one 8B sc1 store ----
    unsigned short* hsrow = hs + (size_t)t * (B_ * H_);
#pragma unroll
    for (int e = 0; e < 4; ++e) {
      unsigned vpair = (unsigned)hbits[e] | ((unsigned)__shfl_xor((int)hbits[e], 1) << 16);
      unsigned long long vquad =
          (unsigned long long)vpair | ((unsigned long long)(unsigned)__shfl_xor((int)vpair, 2) << 32);
      if ((lane & 3) == 0) {
        unsigned long long* dst =
            (unsigned long long*)(hsrow + (size_t)(mD + e) * H_ + jst);
        __hip_atomic_store(dst, vquad, __ATOMIC_RELAXED, __HIP_MEMORY_SCOPE_AGENT);
      }
    }

    // wave-wide drain of own stores, post own flag — no intra-WG coupling
    asm volatile("s_waitcnt vmcnt(0)" ::: "memory");
    if (lane == 0)
      __hip_atomic_store(flags + (w << 2) + wave, (unsigned)(t + 1),
                         __ATOMIC_RELAXED, __HIP_MEMORY_SCOPE_AGENT);

    // next step's x-part (pure register MFMA) overlaps the coming poll
    if (t + 1 < T_) computeX();
  }
}

// ---------------- K3: out[t,b,:] = hs[t,b,:] @ W_fc^T + b_fc ----------------
__global__ void k_fc(const unsigned short* __restrict__ hs, const unsigned short* __restrict__ wfcp,
                     const float* __restrict__ bfc, float* __restrict__ out) {
  const int bm = blockIdx.x >> 2, bn = blockIdx.x & 3;
  const int tid = threadIdx.x, wave = tid >> 6, lane = tid & 63;
  const int r    = bm * 64 + wave * 16 + (lane & 15);
  const int kOff = (lane >> 4) * 8;
  const int nb   = bn * 4;   // first 16-wide n-tile index
  f32x4 acc[4];
#pragma unroll
  for (int nt = 0; nt < 4; ++nt) {
    float bv = bfc[(nb + nt) * 16 + (lane & 15)];
    acc[nt] = {bv, bv, bv, bv};
  }
  const unsigned short* arow = hs + (size_t)r * H_ + kOff;
#pragma unroll 2
  for (int kk = 0; kk < 32; ++kk) {
    bf16x8 a = *(const bf16x8*)(arow + kk * 32);
#pragma unroll
    for (int nt = 0; nt < 4; ++nt) {
      bf16x8 b = *(const bf16x8*)(wfcp + ((size_t)(kk * 16 + nb + nt) * 64 + lane) * 8);
      acc[nt] = __builtin_amdgcn_mfma_f32_16x16x32_bf16(a, b, acc[nt], 0, 0, 0);
    }
  }
  const int ro = bm * 64 + wave * 16 + (lane >> 4) * 4;
#pragma unroll
  for (int nt = 0; nt < 4; ++nt)
#pragma unroll
    for (int e = 0; e < 4; ++e)
      out[(size_t)(ro + e) * I_ + (nb + nt) * 16 + (lane & 15)] = acc[nt][e];
}

// ---------------- launcher ----------------
extern "C" void kernel_launch(void* const* d_in, const int* in_sizes, int n_in,
                              void* d_out, int out_size, void* d_ws, size_t ws_size,
                              hipStream_t stream) {
  const float* x   = (const float*)d_in[0];
  const float* h0  = (const float*)d_in[1];
  const float* c0  = (const float*)d_in[2];
  const float* Wih = (const float*)d_in[3];
  const float* Whh = (const float*)d_in[4];
  const float* bih = (const float*)d_in[5];
  const float* bhh = (const float*)d_in[6];
  const float* Wfc = (const float*)d_in[7];
  const float* bfc = (const float*)d_in[8];
  float* out = (float*)d_out;

  char* ws = (char*)d_ws;
  // ws layout (bytes): total ~95.2 MB
  unsigned short* xb    = (unsigned short*)(ws + 0);           // 16,777,216
  unsigned short* hsb   = (unsigned short*)(ws + 16777216);    // 67,108,864
  unsigned short* wpk   = (unsigned short*)(ws + 83886080);    // 10,485,760
  float*          biasp = (float*)        (ws + 94371840);     //     16,384
  unsigned short* wfcp  = (unsigned short*)(ws + 94388224);    //    524,288
  unsigned short* hbuf  = (unsigned short*)(ws + 94912512);    //    262,144
  unsigned int*   flg   = (unsigned int*)  (ws + 95174656);    //      4,096

  k_pack_x  <<<4096, 256, 0, stream>>>(x, xb);
  k_pack_w  <<<2560, 256, 0, stream>>>(Wih, Whh, bih, bhh, wpk, biasp);
  k_pack_wfc<<<128,  256, 0, stream>>>(Wfc, wfcp);
  k_init_h  <<<32,   256, 0, stream>>>(h0, hbuf, flg);
  k_lstm    <<<NWG,  256, 0, stream>>>(xb, wpk, biasp, c0, hbuf, hsb, flg);
  k_fc      <<<2048, 256, 0, stream>>>(hsb, wfcp, bfc, out);
}

// Round 8
// 5054.345 us; speedup vs baseline: 1.2406x; 1.2406x over previous
//
#include <hip/hip_runtime.h>
#include <hip/hip_bf16.h>

// Problem constants
#define B_    64
#define T_    512
#define I_    256
#define H_    1024
#define KTOT  1280          // I_ + H_
#define KSTEPS 40           // KTOT / 32
#define NWG   128           // recurrence workgroups (each owns NJ h-cols)
#define NJ    8             // h-columns per WG -> 32 gate columns
#define WPK_ELEMS (2 * KSTEPS * 64 * 8)   // 40960 bf16 per WG slice (80KB)

typedef __bf16 bf16x8 __attribute__((ext_vector_type(8)));
typedef float  f32x4  __attribute__((ext_vector_type(4)));

__device__ __forceinline__ unsigned short f2bf(float f) {
  unsigned u = __builtin_bit_cast(unsigned, f);
  u += 0x7FFFu + ((u >> 16) & 1u);       // round-to-nearest-even
  return (unsigned short)(u >> 16);
}
__device__ __forceinline__ float sigm(float x) { return 1.0f / (1.0f + __expf(-x)); }
__device__ __forceinline__ float tanh_fast(float x) {
  float ax = fabsf(x);
  float e  = __expf(-2.0f * ax);          // in (0,1], no overflow
  float t  = (1.0f - e) / (1.0f + e);
  return x < 0.0f ? -t : t;
}

// ---------------- K0: x [B,T,I] f32 -> xb [T,B,I] bf16 ----------------
__global__ void k_pack_x(const float* __restrict__ x, unsigned short* __restrict__ xb) {
  int idx = blockIdx.x * blockDim.x + threadIdx.x;   // over B*T*I/8 = 1,048,576
  int ic = idx & 31;             // I/8 = 32
  int t  = (idx >> 5) & 511;     // T = 512
  int b  = idx >> 14;            // B = 64
  const float* src = x + ((size_t)b * T_ + t) * I_ + ic * 8;
  float4 f0 = *(const float4*)src;
  float4 f1 = *(const float4*)(src + 4);
  unsigned short o[8] = {f2bf(f0.x), f2bf(f0.y), f2bf(f0.z), f2bf(f0.w),
                         f2bf(f1.x), f2bf(f1.y), f2bf(f1.z), f2bf(f1.w)};
  *(uint4*)(xb + ((size_t)t * B_ + b) * I_ + ic * 8) = *(uint4*)o;
}

// ---------------- K1a: pack W_ih|W_hh into per-WG B-fragment layout ----------------
// layout: [w][nt][kk][lane][e], value = W[gate*H + w*NJ + (n&7)][k] with
// n = lane&15 (n<8 -> gate nt*2, n>=8 -> gate nt*2+1), k = kk*32 + (lane>>4)*8 + e
__global__ void k_pack_w(const float* __restrict__ Wih, const float* __restrict__ Whh,
                         const float* __restrict__ bih, const float* __restrict__ bhh,
                         unsigned short* __restrict__ wpack, float* __restrict__ biasp) {
  int f = blockIdx.x * blockDim.x + threadIdx.x;     // 128*2*40*64 = 655,360
  int l  = f & 63;
  int q  = f >> 6;
  int kk = q % KSTEPS;
  int q2 = q / KSTEPS;
  int nt = q2 & 1;
  int w  = q2 >> 1;
  int n  = l & 15;
  int g  = nt * 2 + (n >> 3);
  int r  = g * H_ + w * NJ + (n & 7);
  int k0 = kk * 32 + (l >> 4) * 8;
  unsigned short o[8];
#pragma unroll
  for (int e = 0; e < 8; ++e) {
    int k = k0 + e;
    float v = (k < I_) ? Wih[(size_t)r * I_ + k] : Whh[(size_t)r * H_ + (k - I_)];
    o[e] = f2bf(v);
  }
  *(uint4*)(wpack + (size_t)f * 8) = *(uint4*)o;
  if (kk == 0 && (l >> 4) == 0) biasp[w * 32 + nt * 16 + n] = bih[r] + bhh[r];
}

// ---------------- K1b: pack W_fc [I,H] -> fragment layout [kk][nt][lane][e] ----------------
__global__ void k_pack_wfc(const float* __restrict__ Wfc, unsigned short* __restrict__ wfcp) {
  int f = blockIdx.x * blockDim.x + threadIdx.x;     // 32*16*64 = 32768
  int l  = f & 63;
  int nt = (f >> 6) & 15;
  int kk = f >> 10;
  int n  = nt * 16 + (l & 15);
  int k0 = kk * 32 + (l >> 4) * 8;
  unsigned short o[8];
#pragma unroll
  for (int e = 0; e < 8; ++e) o[e] = f2bf(Wfc[(size_t)n * H_ + k0 + e]);
  *(uint4*)(wfcp + (size_t)f * 8) = *(uint4*)o;
}

// ---------------- K1c: h0 -> bf16 hbuf; zero flags ----------------
__global__ void k_init_h(const float* __restrict__ h0, unsigned short* __restrict__ hbuf,
                         unsigned int* __restrict__ flags) {
  int idx = blockIdx.x * blockDim.x + threadIdx.x;   // B*H/8 = 8192
  const float* s = h0 + (size_t)idx * 8;
  unsigned short o[8];
#pragma unroll
  for (int e = 0; e < 8; ++e) o[e] = f2bf(s[e]);
  *(uint4*)(hbuf + (size_t)idx * 8) = *(uint4*)o;
  if (idx < 1024) flags[idx] = 0;
}

// 12-load / 20-load parallel h-fetch blocks (all loads in flight, one latency)
#define HLOAD12(P)                                                          \
  asm volatile(                                                             \
    "global_load_dwordx4 %0,  %12, off\n\t"                                 \
    "global_load_dwordx4 %1,  %12, off offset:64\n\t"                       \
    "global_load_dwordx4 %2,  %12, off offset:128\n\t"                      \
    "global_load_dwordx4 %3,  %12, off offset:192\n\t"                      \
    "global_load_dwordx4 %4,  %12, off offset:256\n\t"                      \
    "global_load_dwordx4 %5,  %12, off offset:320\n\t"                      \
    "global_load_dwordx4 %6,  %12, off offset:384\n\t"                      \
    "global_load_dwordx4 %7,  %12, off offset:448\n\t"                      \
    "global_load_dwordx4 %8,  %12, off offset:512\n\t"                      \
    "global_load_dwordx4 %9,  %12, off offset:576\n\t"                      \
    "global_load_dwordx4 %10, %12, off offset:640\n\t"                      \
    "global_load_dwordx4 %11, %12, off offset:704\n\t"                      \
    "s_waitcnt vmcnt(0)"                                                    \
    : "=&v"(h00), "=&v"(h01), "=&v"(h02), "=&v"(h03), "=&v"(h04),           \
      "=&v"(h05), "=&v"(h06), "=&v"(h07), "=&v"(h08), "=&v"(h09),           \
      "=&v"(h10), "=&v"(h11)                                                \
    : "v"(P) : "memory")

#define HLOAD20(P)                                                          \
  asm volatile(                                                             \
    "global_load_dwordx4 %0,  %20, off\n\t"                                 \
    "global_load_dwordx4 %1,  %20, off offset:64\n\t"                       \
    "global_load_dwordx4 %2,  %20, off offset:128\n\t"                      \
    "global_load_dwordx4 %3,  %20, off offset:192\n\t"                      \
    "global_load_dwordx4 %4,  %20, off offset:256\n\t"                      \
    "global_load_dwordx4 %5,  %20, off offset:320\n\t"                      \
    "global_load_dwordx4 %6,  %20, off offset:384\n\t"                      \
    "global_load_dwordx4 %7,  %20, off offset:448\n\t"                      \
    "global_load_dwordx4 %8,  %20, off offset:512\n\t"                      \
    "global_load_dwordx4 %9,  %20, off offset:576\n\t"                      \
    "global_load_dwordx4 %10, %20, off offset:640\n\t"                      \
    "global_load_dwordx4 %11, %20, off offset:704\n\t"                      \
    "global_load_dwordx4 %12, %20, off offset:768\n\t"                      \
    "global_load_dwordx4 %13, %20, off offset:832\n\t"                      \
    "global_load_dwordx4 %14, %20, off offset:896\n\t"                      \
    "global_load_dwordx4 %15, %20, off offset:960\n\t"                      \
    "global_load_dwordx4 %16, %20, off offset:1024\n\t"                     \
    "global_load_dwordx4 %17, %20, off offset:1088\n\t"                     \
    "global_load_dwordx4 %18, %20, off offset:1152\n\t"                     \
    "global_load_dwordx4 %19, %20, off offset:1216\n\t"                     \
    "s_waitcnt vmcnt(0)"                                                    \
    : "=&v"(h00), "=&v"(h01), "=&v"(h02), "=&v"(h03), "=&v"(h04),           \
      "=&v"(h05), "=&v"(h06), "=&v"(h07), "=&v"(h08), "=&v"(h09),           \
      "=&v"(h10), "=&v"(h11), "=&v"(h12), "=&v"(h13), "=&v"(h14),           \
      "=&v"(h15), "=&v"(h16), "=&v"(h17), "=&v"(h18), "=&v"(h19)            \
    : "v"(P) : "memory")

// one K-slice: 2 MFMAs (tiles [i|f] and [g|o]) for fragment HF at LDS slot KK
#define STEP_H(HF, KK)                                                              \
  acc0 = __builtin_amdgcn_mfma_f32_16x16x32_bf16(__builtin_bit_cast(bf16x8, HF),    \
         *(const bf16x8*)(wlds + ((size_t)(KK) * 64 + lane) * 8), acc0, 0, 0, 0);   \
  acc1 = __builtin_amdgcn_mfma_f32_16x16x32_bf16(__builtin_bit_cast(bf16x8, HF),    \
         *(const bf16x8*)(wlds + ((size_t)(KSTEPS + (KK)) * 64 + lane) * 8), acc1, 0, 0, 0);

// ---------------- K2: persistent LSTM recurrence ----------------
// 128 WGs x 512 threads (8 waves = 2/SIMD). WG w owns h-cols [w*8, w*8+8).
// Wave PAIR (q, q+4) computes one M=16 x N=32 tile, K split: lead q does
// x-part + LDS slots 8..19 (h frags 0..11); helper q+4 does slots 20..39
// (h frags 12..31) -> partials via LDS + one __syncthreads.
// NOTE mapping: LDS W slot kk multiplies h fragment (kk-8), i.e. h element
// (kk-8)*32 + kOff  (x-part occupies slots 0..7 = first 256 K indices).
// Sync: 512 per-lead-wave flags; sc1 write-through h stores; every wave polls.
__global__ void __launch_bounds__(512, 2) k_lstm(
    const unsigned short* __restrict__ xb, const unsigned short* __restrict__ wpack,
    const float* __restrict__ biasp, const float* __restrict__ c0,
    const unsigned short* __restrict__ hbuf, unsigned short* __restrict__ hs,
    unsigned int* __restrict__ flags) {
  __shared__ unsigned short wlds[WPK_ELEMS];  // 80 KB
  __shared__ f32x4 pacc[4][2][64];            // 8 KB helper partials
  const int w    = blockIdx.x;
  const int tid  = threadIdx.x;
  const int wave = tid >> 6, lane = tid & 63;
  const int q    = wave & 3, hi = wave >> 2;   // hi=0 lead, hi=1 helper

  { // one-time LDS fill of the W slice (512 threads)
    const unsigned short* wp = wpack + (size_t)w * WPK_ELEMS;
    for (int i = tid * 8; i < WPK_ELEMS; i += 512 * 8)
      *(uint4*)(wlds + i) = *(const uint4*)(wp + i);
  }

  const int mA   = q * 16 + (lane & 15);       // A-fragment row = batch index
  const int kOff = (lane >> 4) * 8;            // A-fragment k offset within 32
  const int mD   = q * 16 + (lane >> 4) * 4;   // D-fragment row base
  const int jst  = w * NJ + (lane & 7);        // owned h-column

  float bias0 = 0.f, bias1 = 0.f, creg[4] = {0.f, 0.f, 0.f, 0.f};
  if (hi == 0) {
    bias0 = biasp[w * 32 + (lane & 15)];
    bias1 = biasp[w * 32 + 16 + (lane & 15)];
#pragma unroll
    for (int e = 0; e < 4; ++e) creg[e] = c0[(size_t)(mD + e) * H_ + jst];
  }

  __syncthreads();   // LDS W ready

  bf16x8 xf[8];      // lead: prefetched x fragments for the NEXT step
  f32x4 xacc0, xacc1;
  auto loadX = [&](int t) {
    const unsigned short* xrow = xb + ((size_t)t * B_ + mA) * I_ + kOff;
#pragma unroll
    for (int kk = 0; kk < 8; ++kk) xf[kk] = *(const bf16x8*)(xrow + kk * 32);
  };
  auto computeX = [&]() {
    xacc0 = f32x4{bias0, bias0, bias0, bias0};
    xacc1 = f32x4{bias1, bias1, bias1, bias1};
#pragma unroll
    for (int kk = 0; kk < 8; ++kk) {
      bf16x8 b0 = *(const bf16x8*)(wlds + ((size_t)(kk) * 64 + lane) * 8);
      bf16x8 b1 = *(const bf16x8*)(wlds + ((size_t)(KSTEPS + kk) * 64 + lane) * 8);
      xacc0 = __builtin_amdgcn_mfma_f32_16x16x32_bf16(xf[kk], b0, xacc0, 0, 0, 0);
      xacc1 = __builtin_amdgcn_mfma_f32_16x16x32_bf16(xf[kk], b1, xacc1, 0, 0, 0);
    }
  };
  if (hi == 0) {
    loadX(0);
    asm volatile("" ::: "memory");
    computeX();
  }

  for (int t = 0; t < T_; ++t) {
    // ---- every wave polls all 512 per-lead-wave flags (2 dwordx4/lane) ----
    if (t > 0) {
      const unsigned target = (unsigned)t;
      const uint4* fp = (const uint4*)flags + lane;   // + offset:1024 covers 256..511
      int guard = 0;
      for (;;) {
        uint4 v0, v1;
        asm volatile("global_load_dwordx4 %0, %2, off sc0 sc1\n\t"
                     "global_load_dwordx4 %1, %2, off offset:1024 sc0 sc1\n\t"
                     "s_waitcnt vmcnt(0)"
                     : "=&v"(v0), "=&v"(v1) : "v"(fp) : "memory");
        bool ok = v0.x >= target && v0.y >= target && v0.z >= target && v0.w >= target &&
                  v1.x >= target && v1.y >= target && v1.z >= target && v1.w >= target;
        if (__all(ok)) break;
        if (++guard > (1 << 20)) break;   // safety: never hard-hang
      }
      asm volatile("" ::: "memory");
    }

    const unsigned short* hprev = (t == 0) ? hbuf : hs + (size_t)(t - 1) * (B_ * H_);
    const unsigned short* hrow = hprev + (size_t)mA * H_ + kOff;

    f32x4 acc0, acc1;
    if (hi == 0) {
      // lead: LDS slots 8..19 = h frags 0..11 -> loads start at hrow + 0
      uint4 h00,h01,h02,h03,h04,h05,h06,h07,h08,h09,h10,h11;
      const void* hp = (const void*)(hrow);
      HLOAD12(hp);
      acc0 = xacc0; acc1 = xacc1;
      STEP_H(h00,  8) STEP_H(h01,  9) STEP_H(h02, 10) STEP_H(h03, 11)
      STEP_H(h04, 12) STEP_H(h05, 13) STEP_H(h06, 14) STEP_H(h07, 15)
      STEP_H(h08, 16) STEP_H(h09, 17) STEP_H(h10, 18) STEP_H(h11, 19)
    } else {
      // helper: LDS slots 20..39 = h frags 12..31 -> loads start at hrow + 12*32
      uint4 h00,h01,h02,h03,h04,h05,h06,h07,h08,h09,
            h10,h11,h12,h13,h14,h15,h16,h17,h18,h19;
      const void* hp = (const void*)(hrow + 12 * 32);
      HLOAD20(hp);
      acc0 = f32x4{0.f, 0.f, 0.f, 0.f}; acc1 = f32x4{0.f, 0.f, 0.f, 0.f};
      STEP_H(h00, 20) STEP_H(h01, 21) STEP_H(h02, 22) STEP_H(h03, 23)
      STEP_H(h04, 24) STEP_H(h05, 25) STEP_H(h06, 26) STEP_H(h07, 27)
      STEP_H(h08, 28) STEP_H(h09, 29) STEP_H(h10, 30) STEP_H(h11, 31)
      STEP_H(h12, 32) STEP_H(h13, 33) STEP_H(h14, 34) STEP_H(h15, 35)
      STEP_H(h16, 36) STEP_H(h17, 37) STEP_H(h18, 38) STEP_H(h19, 39)
      pacc[q][0][lane] = acc0;
      pacc[q][1][lane] = acc1;
    }

    __syncthreads();   // helper partials visible to leads

    if (hi == 0) {
      acc0 += pacc[q][0][lane];
      acc1 += pacc[q][1][lane];

      // gates: acc0 = [i|f], acc1 = [g|o]; f/o live in lane^8
      unsigned short hbits[4];
#pragma unroll
      for (int e = 0; e < 4; ++e) {
        float ip  = acc0[e], gp = acc1[e];
        float fp_ = __shfl_xor(ip, 8);
        float op_ = __shfl_xor(gp, 8);
        float ig = sigm(ip), fg = sigm(fp_), gg = tanh_fast(gp), og = sigm(op_);
        float cn = fg * creg[e] + ig * gg;
        creg[e] = cn;
        hbits[e] = f2bf(og * tanh_fast(cn));
      }

      // store h_t: gather 4 adjacent cols into one 8B sc1 store
      unsigned short* hsrow = hs + (size_t)t * (B_ * H_);
#pragma unroll
      for (int e = 0; e < 4; ++e) {
        unsigned vpair = (unsigned)hbits[e] | ((unsigned)__shfl_xor((int)hbits[e], 1) << 16);
        unsigned long long vquad =
            (unsigned long long)vpair |
            ((unsigned long long)(unsigned)__shfl_xor((int)vpair, 2) << 32);
        if ((lane & 11) == 0) {
          unsigned long long* dst =
              (unsigned long long*)(hsrow + (size_t)(mD + e) * H_ + jst);
          __hip_atomic_store(dst, vquad, __ATOMIC_RELAXED, __HIP_MEMORY_SCOPE_AGENT);
        }
      }

      // issue next step's x loads BEFORE the drain (drain covers them)
      if (t + 1 < T_) loadX(t + 1);

      // wave-wide drain of own sc1 stores (+x loads), post own flag
      asm volatile("s_waitcnt vmcnt(0)" ::: "memory");
      if (lane == 0)
        __hip_atomic_store(flags + (w << 2) + q, (unsigned)(t + 1),
                           __ATOMIC_RELAXED, __HIP_MEMORY_SCOPE_AGENT);

      // next step's x-part (registers + LDS only) overlaps the coming poll
      if (t + 1 < T_) computeX();
    }
  }
}

// ---------------- K3: out[t,b,:] = hs[t,b,:] @ W_fc^T + b_fc ----------------
__global__ void k_fc(const unsigned short* __restrict__ hs, const unsigned short* __restrict__ wfcp,
                     const float* __restrict__ bfc, float* __restrict__ out) {
  const int bm = blockIdx.x >> 2, bn = blockIdx.x & 3;
  const int tid = threadIdx.x, wave = tid >> 6, lane = tid & 63;
  const int r    = bm * 64 + wave * 16 + (lane & 15);
  const int kOff = (lane >> 4) * 8;
  const int nb   = bn * 4;   // first 16-wide n-tile index
  f32x4 acc[4];
#pragma unroll
  for (int nt = 0; nt < 4; ++nt) {
    float bv = bfc[(nb + nt) * 16 + (lane & 15)];
    acc[nt] = {bv, bv, bv, bv};
  }
  const unsigned short* arow = hs + (size_t)r * H_ + kOff;
#pragma unroll 2
  for (int kk = 0; kk < 32; ++kk) {
    bf16x8 a = *(const bf16x8*)(arow + kk * 32);
#pragma unroll
    for (int nt = 0; nt < 4; ++nt) {
      bf16x8 b = *(const bf16x8*)(wfcp + ((size_t)(kk * 16 + nb + nt) * 64 + lane) * 8);
      acc[nt] = __builtin_amdgcn_mfma_f32_16x16x32_bf16(a, b, acc[nt], 0, 0, 0);
    }
  }
  const int ro = bm * 64 + wave * 16 + (lane >> 4) * 4;
#pragma unroll
  for (int nt = 0; nt < 4; ++nt)
#pragma unroll
    for (int e = 0; e < 4; ++e)
      out[(size_t)(ro + e) * I_ + (nb + nt) * 16 + (lane & 15)] = acc[nt][e];
}

// ---------------- launcher ----------------
extern "C" void kernel_launch(void* const* d_in, const int* in_sizes, int n_in,
                              void* d_out, int out_size, void* d_ws, size_t ws_size,
                              hipStream_t stream) {
  const float* x   = (const float*)d_in[0];
  const float* h0  = (const float*)d_in[1];
  const float* c0  = (const float*)d_in[2];
  const float* Wih = (const float*)d_in[3];
  const float* Whh = (const float*)d_in[4];
  const float* bih = (const float*)d_in[5];
  const float* bhh = (const float*)d_in[6];
  const float* Wfc = (const float*)d_in[7];
  const float* bfc = (const float*)d_in[8];
  float* out = (float*)d_out;

  char* ws = (char*)d_ws;
  // ws layout (bytes): total ~95.2 MB
  unsigned short* xb    = (unsigned short*)(ws + 0);           // 16,777,216
  unsigned short* hsb   = (unsigned short*)(ws + 16777216);    // 67,108,864
  unsigned short* wpk   = (unsigned short*)(ws + 83886080);    // 10,485,760
  float*          biasp = (float*)        (ws + 94371840);     //     16,384
  unsigned short* wfcp  = (unsigned short*)(ws + 94388224);    //    524,288
  unsigned short* hbuf  = (unsigned short*)(ws + 94912512);    //    262,144
  unsigned int*   flg   = (unsigned int*)  (ws + 95174656);    //      4,096

  k_pack_x  <<<4096, 256, 0, stream>>>(x, xb);
  k_pack_w  <<<2560, 256, 0, stream>>>(Wih, Whh, bih, bhh, wpk, biasp);
  k_pack_wfc<<<128,  256, 0, stream>>>(Wfc, wfcp);
  k_init_h  <<<32,   256, 0, stream>>>(h0, hbuf, flg);
  k_lstm    <<<NWG,  512, 0, stream>>>(xb, wpk, biasp, c0, hbuf, hsb, flg);
  k_fc      <<<2048, 256, 0, stream>>>(hsb, wfcp, bfc, out);
}

// Round 9
// 4586.018 us; speedup vs baseline: 1.3673x; 1.1021x over previous
//
#include <hip/hip_runtime.h>
#include <hip/hip_bf16.h>

// Problem constants
#define B_    64
#define T_    512
#define I_    256
#define H_    1024
#define KTOT  1280          // I_ + H_
#define KSTEPS 40           // KTOT / 32
#define NWG   128           // recurrence workgroups (each owns NJ h-cols)
#define NJ    8             // h-columns per WG -> 32 gate columns
#define WPK_ELEMS (2 * KSTEPS * 64 * 8)   // 40960 bf16 per WG slice (80KB)

typedef __bf16 bf16x8 __attribute__((ext_vector_type(8)));
typedef float  f32x4  __attribute__((ext_vector_type(4)));

__device__ __forceinline__ unsigned short f2bf(float f) {
  unsigned u = __builtin_bit_cast(unsigned, f);
  u += 0x7FFFu + ((u >> 16) & 1u);       // round-to-nearest-even
  return (unsigned short)(u >> 16);
}
__device__ __forceinline__ float sigm(float x) { return 1.0f / (1.0f + __expf(-x)); }
__device__ __forceinline__ float tanh_fast(float x) {
  float ax = fabsf(x);
  float e  = __expf(-2.0f * ax);          // in (0,1], no overflow
  float t  = (1.0f - e) / (1.0f + e);
  return x < 0.0f ? -t : t;
}

// ---------------- K0: x [B,T,I] f32 -> xb [T,B,I] bf16 ----------------
__global__ void k_pack_x(const float* __restrict__ x, unsigned short* __restrict__ xb) {
  int idx = blockIdx.x * blockDim.x + threadIdx.x;   // over B*T*I/8 = 1,048,576
  int ic = idx & 31;             // I/8 = 32
  int t  = (idx >> 5) & 511;     // T = 512
  int b  = idx >> 14;            // B = 64
  const float* src = x + ((size_t)b * T_ + t) * I_ + ic * 8;
  float4 f0 = *(const float4*)src;
  float4 f1 = *(const float4*)(src + 4);
  unsigned short o[8] = {f2bf(f0.x), f2bf(f0.y), f2bf(f0.z), f2bf(f0.w),
                         f2bf(f1.x), f2bf(f1.y), f2bf(f1.z), f2bf(f1.w)};
  *(uint4*)(xb + ((size_t)t * B_ + b) * I_ + ic * 8) = *(uint4*)o;
}

// ---------------- K1a: pack W_ih|W_hh into per-WG B-fragment layout ----------------
// layout: [w][nt][kk][lane][e], value = W[gate*H + w*NJ + (n&7)][k] with
// n = lane&15 (n<8 -> gate nt*2, n>=8 -> gate nt*2+1), k = kk*32 + (lane>>4)*8 + e
__global__ void k_pack_w(const float* __restrict__ Wih, const float* __restrict__ Whh,
                         const float* __restrict__ bih, const float* __restrict__ bhh,
                         unsigned short* __restrict__ wpack, float* __restrict__ biasp) {
  int f = blockIdx.x * blockDim.x + threadIdx.x;     // 128*2*40*64 = 655,360
  int l  = f & 63;
  int q  = f >> 6;
  int kk = q % KSTEPS;
  int q2 = q / KSTEPS;
  int nt = q2 & 1;
  int w  = q2 >> 1;
  int n  = l & 15;
  int g  = nt * 2 + (n >> 3);
  int r  = g * H_ + w * NJ + (n & 7);
  int k0 = kk * 32 + (l >> 4) * 8;
  unsigned short o[8];
#pragma unroll
  for (int e = 0; e < 8; ++e) {
    int k = k0 + e;
    float v = (k < I_) ? Wih[(size_t)r * I_ + k] : Whh[(size_t)r * H_ + (k - I_)];
    o[e] = f2bf(v);
  }
  *(uint4*)(wpack + (size_t)f * 8) = *(uint4*)o;
  if (kk == 0 && (l >> 4) == 0) biasp[w * 32 + nt * 16 + n] = bih[r] + bhh[r];
}

// ---------------- K1b: pack W_fc [I,H] -> fragment layout [kk][nt][lane][e] ----------------
__global__ void k_pack_wfc(const float* __restrict__ Wfc, unsigned short* __restrict__ wfcp) {
  int f = blockIdx.x * blockDim.x + threadIdx.x;     // 32*16*64 = 32768
  int l  = f & 63;
  int nt = (f >> 6) & 15;
  int kk = f >> 10;
  int n  = nt * 16 + (l & 15);
  int k0 = kk * 32 + (l >> 4) * 8;
  unsigned short o[8];
#pragma unroll
  for (int e = 0; e < 8; ++e) o[e] = f2bf(Wfc[(size_t)n * H_ + k0 + e]);
  *(uint4*)(wfcp + (size_t)f * 8) = *(uint4*)o;
}

// ---------------- K1c: h0 -> bf16 hbuf; zero flags ----------------
__global__ void k_init_h(const float* __restrict__ h0, unsigned short* __restrict__ hbuf,
                         unsigned int* __restrict__ flags) {
  int idx = blockIdx.x * blockDim.x + threadIdx.x;   // B*H/8 = 8192
  const float* s = h0 + (size_t)idx * 8;
  unsigned short o[8];
#pragma unroll
  for (int e = 0; e < 8; ++e) o[e] = f2bf(s[e]);
  *(uint4*)(hbuf + (size_t)idx * 8) = *(uint4*)o;
  if (idx < 1024) flags[idx] = 0;
}

// 32 parallel h-fragment loads (one address, imm offsets 0..1984), single wait.
#define HLOAD32(P)                                                          \
  asm volatile(                                                             \
    "global_load_dwordx4 %0,  %32, off\n\t"                                 \
    "global_load_dwordx4 %1,  %32, off offset:64\n\t"                       \
    "global_load_dwordx4 %2,  %32, off offset:128\n\t"                      \
    "global_load_dwordx4 %3,  %32, off offset:192\n\t"                      \
    "global_load_dwordx4 %4,  %32, off offset:256\n\t"                      \
    "global_load_dwordx4 %5,  %32, off offset:320\n\t"                      \
    "global_load_dwordx4 %6,  %32, off offset:384\n\t"                      \
    "global_load_dwordx4 %7,  %32, off offset:448\n\t"                      \
    "global_load_dwordx4 %8,  %32, off offset:512\n\t"                      \
    "global_load_dwordx4 %9,  %32, off offset:576\n\t"                      \
    "global_load_dwordx4 %10, %32, off offset:640\n\t"                      \
    "global_load_dwordx4 %11, %32, off offset:704\n\t"                      \
    "global_load_dwordx4 %12, %32, off offset:768\n\t"                      \
    "global_load_dwordx4 %13, %32, off offset:832\n\t"                      \
    "global_load_dwordx4 %14, %32, off offset:896\n\t"                      \
    "global_load_dwordx4 %15, %32, off offset:960\n\t"                      \
    "global_load_dwordx4 %16, %32, off offset:1024\n\t"                     \
    "global_load_dwordx4 %17, %32, off offset:1088\n\t"                     \
    "global_load_dwordx4 %18, %32, off offset:1152\n\t"                     \
    "global_load_dwordx4 %19, %32, off offset:1216\n\t"                     \
    "global_load_dwordx4 %20, %32, off offset:1280\n\t"                     \
    "global_load_dwordx4 %21, %32, off offset:1344\n\t"                     \
    "global_load_dwordx4 %22, %32, off offset:1408\n\t"                     \
    "global_load_dwordx4 %23, %32, off offset:1472\n\t"                     \
    "global_load_dwordx4 %24, %32, off offset:1536\n\t"                     \
    "global_load_dwordx4 %25, %32, off offset:1600\n\t"                     \
    "global_load_dwordx4 %26, %32, off offset:1664\n\t"                     \
    "global_load_dwordx4 %27, %32, off offset:1728\n\t"                     \
    "global_load_dwordx4 %28, %32, off offset:1792\n\t"                     \
    "global_load_dwordx4 %29, %32, off offset:1856\n\t"                     \
    "global_load_dwordx4 %30, %32, off offset:1920\n\t"                     \
    "global_load_dwordx4 %31, %32, off offset:1984\n\t"                     \
    "s_waitcnt vmcnt(0)"                                                    \
    : "=&v"(h00), "=&v"(h01), "=&v"(h02), "=&v"(h03), "=&v"(h04),           \
      "=&v"(h05), "=&v"(h06), "=&v"(h07), "=&v"(h08), "=&v"(h09),           \
      "=&v"(h10), "=&v"(h11), "=&v"(h12), "=&v"(h13), "=&v"(h14),           \
      "=&v"(h15), "=&v"(h16), "=&v"(h17), "=&v"(h18), "=&v"(h19),           \
      "=&v"(h20), "=&v"(h21), "=&v"(h22), "=&v"(h23), "=&v"(h24),           \
      "=&v"(h25), "=&v"(h26), "=&v"(h27), "=&v"(h28), "=&v"(h29),           \
      "=&v"(h30), "=&v"(h31)                                                \
    : "v"(P) : "memory")

// one K-slice: 2 MFMAs (tiles [i|f] and [g|o]) for fragment HF at LDS slot KK
// (LDS W slot kk multiplies h fragment kk-8; x-part owns slots 0..7)
#define STEP_H(HF, KK)                                                              \
  acc0 = __builtin_amdgcn_mfma_f32_16x16x32_bf16(__builtin_bit_cast(bf16x8, HF),    \
         *(const bf16x8*)(wlds + ((size_t)(KK) * 64 + lane) * 8), acc0, 0, 0, 0);   \
  acc1 = __builtin_amdgcn_mfma_f32_16x16x32_bf16(__builtin_bit_cast(bf16x8, HF),    \
         *(const bf16x8*)(wlds + ((size_t)(KSTEPS + (KK)) * 64 + lane) * 8), acc1, 0, 0, 0);

// ---------------- K2: persistent LSTM recurrence ----------------
// 128 WGs x 256 threads (4 fully decoupled waves, no in-loop __syncthreads).
// WG w owns h-cols [w*8, w*8+8); W slice resident in LDS (80 KB).
// Per step per wave: poll 512 per-wave flags (2 coalesced dwordx4 sc0sc1) ->
// 32 h-fragment loads in ONE asm block (single MALL latency) -> 64 MFMA ->
// gates -> sc1 write-through h stores -> vmcnt(0) drain (stores only) ->
// post own flag EARLY -> issue x(t+1) loads -> computeX overlaps next poll.
__global__ void __launch_bounds__(256, 1) k_lstm(
    const unsigned short* __restrict__ xb, const unsigned short* __restrict__ wpack,
    const float* __restrict__ biasp, const float* __restrict__ c0,
    const unsigned short* __restrict__ hbuf, unsigned short* __restrict__ hs,
    unsigned int* __restrict__ flags) {
  __shared__ unsigned short wlds[WPK_ELEMS];  // 80 KB
  const int w    = blockIdx.x;
  const int tid  = threadIdx.x;
  const int wave = tid >> 6, lane = tid & 63;

  { // one-time LDS fill of the W slice
    const unsigned short* wp = wpack + (size_t)w * WPK_ELEMS;
    for (int i = tid * 8; i < WPK_ELEMS; i += 256 * 8)
      *(uint4*)(wlds + i) = *(const uint4*)(wp + i);
  }

  const int mA   = wave * 16 + (lane & 15);    // A-fragment row = batch index
  const int kOff = (lane >> 4) * 8;            // A-fragment k offset within 32
  const int mD   = wave * 16 + (lane >> 4) * 4;// D-fragment row base
  const int jst  = w * NJ + (lane & 7);        // owned h-column

  const float bias0 = biasp[w * 32 + (lane & 15)];
  const float bias1 = biasp[w * 32 + 16 + (lane & 15)];
  float creg[4];
#pragma unroll
  for (int e = 0; e < 4; ++e) creg[e] = c0[(size_t)(mD + e) * H_ + jst];

  __syncthreads();   // LDS W ready

  bf16x8 xf[8];      // prefetched x fragments for the NEXT step
  f32x4 xacc0, xacc1;
  auto loadX = [&](int t) {
    const unsigned short* xrow = xb + ((size_t)t * B_ + mA) * I_ + kOff;
#pragma unroll
    for (int kk = 0; kk < 8; ++kk) xf[kk] = *(const bf16x8*)(xrow + kk * 32);
  };
  auto computeX = [&]() {   // xf registers + LDS W only
    xacc0 = f32x4{bias0, bias0, bias0, bias0};
    xacc1 = f32x4{bias1, bias1, bias1, bias1};
#pragma unroll
    for (int kk = 0; kk < 8; ++kk) {
      bf16x8 b0 = *(const bf16x8*)(wlds + ((size_t)(kk) * 64 + lane) * 8);
      bf16x8 b1 = *(const bf16x8*)(wlds + ((size_t)(KSTEPS + kk) * 64 + lane) * 8);
      xacc0 = __builtin_amdgcn_mfma_f32_16x16x32_bf16(xf[kk], b0, xacc0, 0, 0, 0);
      xacc1 = __builtin_amdgcn_mfma_f32_16x16x32_bf16(xf[kk], b1, xacc1, 0, 0, 0);
    }
  };
  loadX(0);
  asm volatile("" ::: "memory");
  computeX();

  for (int t = 0; t < T_; ++t) {
    // ---- poll all 512 per-wave flags (2 coalesced dwordx4, cache-bypass) ----
    if (t > 0) {
      const unsigned target = (unsigned)t;
      const uint4* fp = (const uint4*)flags + lane;   // +offset:1024 covers 256..511
      int guard = 0;
      for (;;) {
        uint4 v0, v1;
        asm volatile("global_load_dwordx4 %0, %2, off sc0 sc1\n\t"
                     "global_load_dwordx4 %1, %2, off offset:1024 sc0 sc1\n\t"
                     "s_waitcnt vmcnt(0)"
                     : "=&v"(v0), "=&v"(v1) : "v"(fp) : "memory");
        bool ok = v0.x >= target && v0.y >= target && v0.z >= target && v0.w >= target &&
                  v1.x >= target && v1.y >= target && v1.z >= target && v1.w >= target;
        if (__all(ok)) break;
        if (++guard > (1 << 20)) break;   // safety: never hard-hang
      }
      asm volatile("" ::: "memory");
    }

    // ---- 32 h fragments, one parallel load block ----
    const unsigned short* hprev = (t == 0) ? hbuf : hs + (size_t)(t - 1) * (B_ * H_);
    const unsigned short* hrow = hprev + (size_t)mA * H_ + kOff;
    uint4 h00,h01,h02,h03,h04,h05,h06,h07,h08,h09,h10,h11,h12,h13,h14,h15,
          h16,h17,h18,h19,h20,h21,h22,h23,h24,h25,h26,h27,h28,h29,h30,h31;
    HLOAD32(hrow);

    f32x4 acc0 = xacc0, acc1 = xacc1;
    STEP_H(h00,  8) STEP_H(h01,  9) STEP_H(h02, 10) STEP_H(h03, 11)
    STEP_H(h04, 12) STEP_H(h05, 13) STEP_H(h06, 14) STEP_H(h07, 15)
    STEP_H(h08, 16) STEP_H(h09, 17) STEP_H(h10, 18) STEP_H(h11, 19)
    STEP_H(h12, 20) STEP_H(h13, 21) STEP_H(h14, 22) STEP_H(h15, 23)
    STEP_H(h16, 24) STEP_H(h17, 25) STEP_H(h18, 26) STEP_H(h19, 27)
    STEP_H(h20, 28) STEP_H(h21, 29) STEP_H(h22, 30) STEP_H(h23, 31)
    STEP_H(h24, 32) STEP_H(h25, 33) STEP_H(h26, 34) STEP_H(h27, 35)
    STEP_H(h28, 36) STEP_H(h29, 37) STEP_H(h30, 38) STEP_H(h31, 39)

    // gates: acc0 = [i|f], acc1 = [g|o]; f/o live in lane^8
    unsigned short hbits[4];
#pragma unroll
    for (int e = 0; e < 4; ++e) {
      float ip  = acc0[e], gp = acc1[e];
      float fp_ = __shfl_xor(ip, 8);
      float op_ = __shfl_xor(gp, 8);
      float ig = sigm(ip), fg = sigm(fp_), gg = tanh_fast(gp), og = sigm(op_);
      float cn = fg * creg[e] + ig * gg;
      creg[e] = cn;
      hbits[e] = f2bf(og * tanh_fast(cn));
    }

    // store h_t: gather 4 adjacent cols into one 8B sc1 store
    unsigned short* hsrow = hs + (size_t)t * (B_ * H_);
#pragma unroll
    for (int e = 0; e < 4; ++e) {
      unsigned vpair = (unsigned)hbits[e] | ((unsigned)__shfl_xor((int)hbits[e], 1) << 16);
      unsigned long long vquad =
          (unsigned long long)vpair |
          ((unsigned long long)(unsigned)__shfl_xor((int)vpair, 2) << 32);
      if ((lane & 11) == 0) {   // lanes 0,4,16,20,32,36,48,52
        unsigned long long* dst =
            (unsigned long long*)(hsrow + (size_t)(mD + e) * H_ + jst);
        __hip_atomic_store(dst, vquad, __ATOMIC_RELAXED, __HIP_MEMORY_SCOPE_AGENT);
      }
    }

    // drain ONLY the h stores (h loads already consumed; x not yet issued),
    // then post own flag as early as possible
    asm volatile("s_waitcnt vmcnt(0)" ::: "memory");
    if (lane == 0)
      __hip_atomic_store(flags + (w << 2) + wave, (unsigned)(t + 1),
                         __ATOMIC_RELAXED, __HIP_MEMORY_SCOPE_AGENT);

    // x(t+1) load + x-part MFMA overlap the coming poll window
    if (t + 1 < T_) {
      loadX(t + 1);
      computeX();
    }
  }
}

// ---------------- K3: out[t,b,:] = hs[t,b,:] @ W_fc^T + b_fc ----------------
__global__ void k_fc(const unsigned short* __restrict__ hs, const unsigned short* __restrict__ wfcp,
                     const float* __restrict__ bfc, float* __restrict__ out) {
  const int bm = blockIdx.x >> 2, bn = blockIdx.x & 3;
  const int tid = threadIdx.x, wave = tid >> 6, lane = tid & 63;
  const int r    = bm * 64 + wave * 16 + (lane & 15);
  const int kOff = (lane >> 4) * 8;
  const int nb   = bn * 4;   // first 16-wide n-tile index
  f32x4 acc[4];
#pragma unroll
  for (int nt = 0; nt < 4; ++nt) {
    float bv = bfc[(nb + nt) * 16 + (lane & 15)];
    acc[nt] = {bv, bv, bv, bv};
  }
  const unsigned short* arow = hs + (size_t)r * H_ + kOff;
#pragma unroll 2
  for (int kk = 0; kk < 32; ++kk) {
    bf16x8 a = *(const bf16x8*)(arow + kk * 32);
#pragma unroll
    for (int nt = 0; nt < 4; ++nt) {
      bf16x8 b = *(const bf16x8*)(wfcp + ((size_t)(kk * 16 + nb + nt) * 64 + lane) * 8);
      acc[nt] = __builtin_amdgcn_mfma_f32_16x16x32_bf16(a, b, acc[nt], 0, 0, 0);
    }
  }
  const int ro = bm * 64 + wave * 16 + (lane >> 4) * 4;
#pragma unroll
  for (int nt = 0; nt < 4; ++nt)
#pragma unroll
    for (int e = 0; e < 4; ++e)
      out[(size_t)(ro + e) * I_ + (nb + nt) * 16 + (lane & 15)] = acc[nt][e];
}

// ---------------- launcher ----------------
extern "C" void kernel_launch(void* const* d_in, const int* in_sizes, int n_in,
                              void* d_out, int out_size, void* d_ws, size_t ws_size,
                              hipStream_t stream) {
  const float* x   = (const float*)d_in[0];
  const float* h0  = (const float*)d_in[1];
  const float* c0  = (const float*)d_in[2];
  const float* Wih = (const float*)d_in[3];
  const float* Whh = (const float*)d_in[4];
  const float* bih = (const float*)d_in[5];
  const float* bhh = (const float*)d_in[6];
  const float* Wfc = (const float*)d_in[7];
  const float* bfc = (const float*)d_in[8];
  float* out = (float*)d_out;

  char* ws = (char*)d_ws;
  // ws layout (bytes): total ~95.2 MB
  unsigned short* xb    = (unsigned short*)(ws + 0);           // 16,777,216
  unsigned short* hsb   = (unsigned short*)(ws + 16777216);    // 67,108,864
  unsigned short* wpk   = (unsigned short*)(ws + 83886080);    // 10,485,760
  float*          biasp = (float*)        (ws + 94371840);     //     16,384
  unsigned short* wfcp  = (unsigned short*)(ws + 94388224);    //    524,288
  unsigned short* hbuf  = (unsigned short*)(ws + 94912512);    //    262,144
  unsigned int*   flg   = (unsigned int*)  (ws + 95174656);    //      4,096

  k_pack_x  <<<4096, 256, 0, stream>>>(x, xb);
  k_pack_w  <<<2560, 256, 0, stream>>>(Wih, Whh, bih, bhh, wpk, biasp);
  k_pack_wfc<<<128,  256, 0, stream>>>(Wfc, wfcp);
  k_init_h  <<<32,   256, 0, stream>>>(h0, hbuf, flg);
  k_lstm    <<<NWG,  256, 0, stream>>>(xb, wpk, biasp, c0, hbuf, hsb, flg);
  k_fc      <<<2048, 256, 0, stream>>>(hsb, wfcp, bfc, out);
}

// Round 10
// 4438.102 us; speedup vs baseline: 1.4129x; 1.0333x over previous
//
#include <hip/hip_runtime.h>
#include <hip/hip_bf16.h>

// Problem constants
#define B_    64
#define T_    512
#define I_    256
#define H_    1024
#define KTOT  1280          // I_ + H_
#define KSTEPS 40           // KTOT / 32
#define NWG   128           // recurrence workgroups (each owns NJ h-cols)
#define NJ    8             // h-columns per WG -> 32 gate columns
#define WPK_ELEMS (2 * KSTEPS * 64 * 8)   // 40960 bf16 per WG slice (80KB)

typedef __bf16 bf16x8 __attribute__((ext_vector_type(8)));
typedef float  f32x4  __attribute__((ext_vector_type(4)));

__device__ __forceinline__ unsigned short f2bf(float f) {
  unsigned u = __builtin_bit_cast(unsigned, f);
  u += 0x7FFFu + ((u >> 16) & 1u);       // round-to-nearest-even
  return (unsigned short)(u >> 16);
}
__device__ __forceinline__ float sigm(float x) { return 1.0f / (1.0f + __expf(-x)); }
__device__ __forceinline__ float tanh_fast(float x) {
  float ax = fabsf(x);
  float e  = __expf(-2.0f * ax);          // in (0,1], no overflow
  float t  = (1.0f - e) / (1.0f + e);
  return x < 0.0f ? -t : t;
}

// ---------------- K0: x [B,T,I] f32 -> xb [T,B,I] bf16 ----------------
__global__ void k_pack_x(const float* __restrict__ x, unsigned short* __restrict__ xb) {
  int idx = blockIdx.x * blockDim.x + threadIdx.x;   // over B*T*I/8 = 1,048,576
  int ic = idx & 31;             // I/8 = 32
  int t  = (idx >> 5) & 511;     // T = 512
  int b  = idx >> 14;            // B = 64
  const float* src = x + ((size_t)b * T_ + t) * I_ + ic * 8;
  float4 f0 = *(const float4*)src;
  float4 f1 = *(const float4*)(src + 4);
  unsigned short o[8] = {f2bf(f0.x), f2bf(f0.y), f2bf(f0.z), f2bf(f0.w),
                         f2bf(f1.x), f2bf(f1.y), f2bf(f1.z), f2bf(f1.w)};
  *(uint4*)(xb + ((size_t)t * B_ + b) * I_ + ic * 8) = *(uint4*)o;
}

// ---------------- K1a: pack W_ih|W_hh into per-WG B-fragment layout ----------------
// layout: [w][nt][kk][lane][e], value = W[gate*H + w*NJ + (n&7)][k] with
// n = lane&15 (n<8 -> gate nt*2, n>=8 -> gate nt*2+1), k = kk*32 + (lane>>4)*8 + e
__global__ void k_pack_w(const float* __restrict__ Wih, const float* __restrict__ Whh,
                         const float* __restrict__ bih, const float* __restrict__ bhh,
                         unsigned short* __restrict__ wpack, float* __restrict__ biasp) {
  int f = blockIdx.x * blockDim.x + threadIdx.x;     // 128*2*40*64 = 655,360
  int l  = f & 63;
  int q  = f >> 6;
  int kk = q % KSTEPS;
  int q2 = q / KSTEPS;
  int nt = q2 & 1;
  int w  = q2 >> 1;
  int n  = l & 15;
  int g  = nt * 2 + (n >> 3);
  int r  = g * H_ + w * NJ + (n & 7);
  int k0 = kk * 32 + (l >> 4) * 8;
  unsigned short o[8];
#pragma unroll
  for (int e = 0; e < 8; ++e) {
    int k = k0 + e;
    float v = (k < I_) ? Wih[(size_t)r * I_ + k] : Whh[(size_t)r * H_ + (k - I_)];
    o[e] = f2bf(v);
  }
  *(uint4*)(wpack + (size_t)f * 8) = *(uint4*)o;
  if (kk == 0 && (l >> 4) == 0) biasp[w * 32 + nt * 16 + n] = bih[r] + bhh[r];
}

// ---------------- K1b: pack W_fc [I,H] -> fragment layout [kk][nt][lane][e] ----------------
__global__ void k_pack_wfc(const float* __restrict__ Wfc, unsigned short* __restrict__ wfcp) {
  int f = blockIdx.x * blockDim.x + threadIdx.x;     // 32*16*64 = 32768
  int l  = f & 63;
  int nt = (f >> 6) & 15;
  int kk = f >> 10;
  int n  = nt * 16 + (l & 15);
  int k0 = kk * 32 + (l >> 4) * 8;
  unsigned short o[8];
#pragma unroll
  for (int e = 0; e < 8; ++e) o[e] = f2bf(Wfc[(size_t)n * H_ + k0 + e]);
  *(uint4*)(wfcp + (size_t)f * 8) = *(uint4*)o;
}

// ---------------- K1c: h0 -> bf16 hbuf; zero flags ----------------
__global__ void k_init_h(const float* __restrict__ h0, unsigned short* __restrict__ hbuf,
                         unsigned int* __restrict__ flags) {
  int idx = blockIdx.x * blockDim.x + threadIdx.x;   // B*H/8 = 8192
  const float* s = h0 + (size_t)idx * 8;
  unsigned short o[8];
#pragma unroll
  for (int e = 0; e < 8; ++e) o[e] = f2bf(s[e]);
  *(uint4*)(hbuf + (size_t)idx * 8) = *(uint4*)o;
  if (idx < 1024) flags[idx] = 0;
}

// 32 parallel h-fragment loads (one address, imm offsets 0..1984), single wait.
#define HLOAD32(P)                                                          \
  asm volatile(                                                             \
    "global_load_dwordx4 %0,  %32, off\n\t"                                 \
    "global_load_dwordx4 %1,  %32, off offset:64\n\t"                       \
    "global_load_dwordx4 %2,  %32, off offset:128\n\t"                      \
    "global_load_dwordx4 %3,  %32, off offset:192\n\t"                      \
    "global_load_dwordx4 %4,  %32, off offset:256\n\t"                      \
    "global_load_dwordx4 %5,  %32, off offset:320\n\t"                      \
    "global_load_dwordx4 %6,  %32, off offset:384\n\t"                      \
    "global_load_dwordx4 %7,  %32, off offset:448\n\t"                      \
    "global_load_dwordx4 %8,  %32, off offset:512\n\t"                      \
    "global_load_dwordx4 %9,  %32, off offset:576\n\t"                      \
    "global_load_dwordx4 %10, %32, off offset:640\n\t"                      \
    "global_load_dwordx4 %11, %32, off offset:704\n\t"                      \
    "global_load_dwordx4 %12, %32, off offset:768\n\t"                      \
    "global_load_dwordx4 %13, %32, off offset:832\n\t"                      \
    "global_load_dwordx4 %14, %32, off offset:896\n\t"                      \
    "global_load_dwordx4 %15, %32, off offset:960\n\t"                      \
    "global_load_dwordx4 %16, %32, off offset:1024\n\t"                     \
    "global_load_dwordx4 %17, %32, off offset:1088\n\t"                     \
    "global_load_dwordx4 %18, %32, off offset:1152\n\t"                     \
    "global_load_dwordx4 %19, %32, off offset:1216\n\t"                     \
    "global_load_dwordx4 %20, %32, off offset:1280\n\t"                     \
    "global_load_dwordx4 %21, %32, off offset:1344\n\t"                     \
    "global_load_dwordx4 %22, %32, off offset:1408\n\t"                     \
    "global_load_dwordx4 %23, %32, off offset:1472\n\t"                     \
    "global_load_dwordx4 %24, %32, off offset:1536\n\t"                     \
    "global_load_dwordx4 %25, %32, off offset:1600\n\t"                     \
    "global_load_dwordx4 %26, %32, off offset:1664\n\t"                     \
    "global_load_dwordx4 %27, %32, off offset:1728\n\t"                     \
    "global_load_dwordx4 %28, %32, off offset:1792\n\t"                     \
    "global_load_dwordx4 %29, %32, off offset:1856\n\t"                     \
    "global_load_dwordx4 %30, %32, off offset:1920\n\t"                     \
    "global_load_dwordx4 %31, %32, off offset:1984\n\t"                     \
    "s_waitcnt vmcnt(0)"                                                    \
    : "=&v"(h00), "=&v"(h01), "=&v"(h02), "=&v"(h03), "=&v"(h04),           \
      "=&v"(h05), "=&v"(h06), "=&v"(h07), "=&v"(h08), "=&v"(h09),           \
      "=&v"(h10), "=&v"(h11), "=&v"(h12), "=&v"(h13), "=&v"(h14),           \
      "=&v"(h15), "=&v"(h16), "=&v"(h17), "=&v"(h18), "=&v"(h19),           \
      "=&v"(h20), "=&v"(h21), "=&v"(h22), "=&v"(h23), "=&v"(h24),           \
      "=&v"(h25), "=&v"(h26), "=&v"(h27), "=&v"(h28), "=&v"(h29),           \
      "=&v"(h30), "=&v"(h31)                                                \
    : "v"(P) : "memory")

// one K-slice: 2 MFMAs, B operands from the register-resident W (wh0/wh1)
#define STEP_H(HF, I)                                                               \
  acc0 = __builtin_amdgcn_mfma_f32_16x16x32_bf16(__builtin_bit_cast(bf16x8, HF),    \
                                                 wh0[I], acc0, 0, 0, 0);            \
  acc1 = __builtin_amdgcn_mfma_f32_16x16x32_bf16(__builtin_bit_cast(bf16x8, HF),    \
                                                 wh1[I], acc1, 0, 0, 0);

// ---------------- K2: persistent LSTM recurrence ----------------
// 128 WGs x 256 threads (4 fully decoupled waves, no in-loop __syncthreads).
// WG w owns h-cols [w*8, w*8+8). h-part W (2 tiles x 32 kk x 16B/lane = 256
// regs/lane) lives in the unified VGPR/AGPR register file -> the 64-MFMA
// k-loop is pure register compute, zero LDS traffic on the critical path.
// x-part W (16 KB) stays in LDS, consumed only in the post-flag shadow.
// Sync: per-wave flags; h via sc1 write-through; poll with DEVICE-scope (sc1)
// coalesced dwordx4 loads (was system-scope sc0 sc1 -> host coherence point).
__global__ void __launch_bounds__(256, 1) k_lstm(
    const unsigned short* __restrict__ xb, const unsigned short* __restrict__ wpack,
    const float* __restrict__ biasp, const float* __restrict__ c0,
    const unsigned short* __restrict__ hbuf, unsigned short* __restrict__ hs,
    unsigned int* __restrict__ flags) {
  __shared__ unsigned short xlds[2 * 8 * 64 * 8];   // 16 KB: x-part W only
  const int w    = blockIdx.x;
  const int tid  = threadIdx.x;
  const int wave = tid >> 6, lane = tid & 63;

  const uint4* wp4 = (const uint4*)wpack + (size_t)w * (2 * KSTEPS * 64);

  { // x-part W (slots 0..7, both tiles) into LDS
    uint4* xl4 = (uint4*)xlds;
    for (int i = tid; i < 1024; i += 256) {
      int nt = i >> 9, kk = (i >> 6) & 7, l = i & 63;
      xl4[i] = wp4[(size_t)(nt * KSTEPS + kk) * 64 + l];
    }
  }

  // h-part W (slots 8..39, both tiles) into registers: 256 regs/lane
  bf16x8 wh0[32], wh1[32];
#pragma unroll
  for (int i = 0; i < 32; ++i) {
    wh0[i] = __builtin_bit_cast(bf16x8, wp4[(size_t)(8 + i) * 64 + lane]);
    wh1[i] = __builtin_bit_cast(bf16x8, wp4[(size_t)(KSTEPS + 8 + i) * 64 + lane]);
  }

  const int mA   = wave * 16 + (lane & 15);    // A-fragment row = batch index
  const int kOff = (lane >> 4) * 8;            // A-fragment k offset within 32
  const int mD   = wave * 16 + (lane >> 4) * 4;// D-fragment row base
  const int jst  = w * NJ + (lane & 7);        // owned h-column

  const float bias0 = biasp[w * 32 + (lane & 15)];
  const float bias1 = biasp[w * 32 + 16 + (lane & 15)];
  float creg[4];
#pragma unroll
  for (int e = 0; e < 4; ++e) creg[e] = c0[(size_t)(mD + e) * H_ + jst];

  __syncthreads();   // LDS x-W ready

  f32x4 xacc0, xacc1;
  // x-part of step t: global x loads + LDS B reads + 16 MFMA, all in the
  // post-flag shadow (never on the inter-step critical path)
  auto computeX = [&](int t) {
    xacc0 = f32x4{bias0, bias0, bias0, bias0};
    xacc1 = f32x4{bias1, bias1, bias1, bias1};
    const unsigned short* xrow = xb + ((size_t)t * B_ + mA) * I_ + kOff;
#pragma unroll
    for (int kk = 0; kk < 8; ++kk) {
      bf16x8 a  = *(const bf16x8*)(xrow + kk * 32);
      bf16x8 b0 = *(const bf16x8*)(xlds + ((size_t)(kk) * 64 + lane) * 8);
      bf16x8 b1 = *(const bf16x8*)(xlds + ((size_t)(8 + kk) * 64 + lane) * 8);
      xacc0 = __builtin_amdgcn_mfma_f32_16x16x32_bf16(a, b0, xacc0, 0, 0, 0);
      xacc1 = __builtin_amdgcn_mfma_f32_16x16x32_bf16(a, b1, xacc1, 0, 0, 0);
    }
  };
  computeX(0);

  for (int t = 0; t < T_; ++t) {
    // ---- poll all 512 per-wave flags: DEVICE scope (sc1), coalesced ----
    if (t > 0) {
      const unsigned target = (unsigned)t;
      const uint4* fp = (const uint4*)flags + lane;   // +offset:1024 covers 256..511
      int guard = 0;
      for (;;) {
        uint4 v0, v1;
        asm volatile("global_load_dwordx4 %0, %2, off sc1\n\t"
                     "global_load_dwordx4 %1, %2, off offset:1024 sc1\n\t"
                     "s_waitcnt vmcnt(0)"
                     : "=&v"(v0), "=&v"(v1) : "v"(fp) : "memory");
        bool ok = v0.x >= target && v0.y >= target && v0.z >= target && v0.w >= target &&
                  v1.x >= target && v1.y >= target && v1.z >= target && v1.w >= target;
        if (__all(ok)) break;
        if (++guard > (1 << 20)) break;   // safety: never hard-hang
      }
      asm volatile("" ::: "memory");
    }

    // ---- 32 h fragments, one parallel load block ----
    const unsigned short* hprev = (t == 0) ? hbuf : hs + (size_t)(t - 1) * (B_ * H_);
    const unsigned short* hrow = hprev + (size_t)mA * H_ + kOff;
    uint4 h00,h01,h02,h03,h04,h05,h06,h07,h08,h09,h10,h11,h12,h13,h14,h15,
          h16,h17,h18,h19,h20,h21,h22,h23,h24,h25,h26,h27,h28,h29,h30,h31;
    HLOAD32(hrow);

    // ---- 64 MFMAs, all operands in registers ----
    f32x4 acc0 = xacc0, acc1 = xacc1;
    STEP_H(h00,  0) STEP_H(h01,  1) STEP_H(h02,  2) STEP_H(h03,  3)
    STEP_H(h04,  4) STEP_H(h05,  5) STEP_H(h06,  6) STEP_H(h07,  7)
    STEP_H(h08,  8) STEP_H(h09,  9) STEP_H(h10, 10) STEP_H(h11, 11)
    STEP_H(h12, 12) STEP_H(h13, 13) STEP_H(h14, 14) STEP_H(h15, 15)
    STEP_H(h16, 16) STEP_H(h17, 17) STEP_H(h18, 18) STEP_H(h19, 19)
    STEP_H(h20, 20) STEP_H(h21, 21) STEP_H(h22, 22) STEP_H(h23, 23)
    STEP_H(h24, 24) STEP_H(h25, 25) STEP_H(h26, 26) STEP_H(h27, 27)
    STEP_H(h28, 28) STEP_H(h29, 29) STEP_H(h30, 30) STEP_H(h31, 31)

    // gates: acc0 = [i|f], acc1 = [g|o]; f/o live in lane^8
    unsigned short hbits[4];
#pragma unroll
    for (int e = 0; e < 4; ++e) {
      float ip  = acc0[e], gp = acc1[e];
      float fp_ = __shfl_xor(ip, 8);
      float op_ = __shfl_xor(gp, 8);
      float ig = sigm(ip), fg = sigm(fp_), gg = tanh_fast(gp), og = sigm(op_);
      float cn = fg * creg[e] + ig * gg;
      creg[e] = cn;
      hbits[e] = f2bf(og * tanh_fast(cn));
    }

    // store h_t: gather 4 adjacent cols into one 8B sc1 store
    unsigned short* hsrow = hs + (size_t)t * (B_ * H_);
#pragma unroll
    for (int e = 0; e < 4; ++e) {
      unsigned vpair = (unsigned)hbits[e] | ((unsigned)__shfl_xor((int)hbits[e], 1) << 16);
      unsigned long long vquad =
          (unsigned long long)vpair |
          ((unsigned long long)(unsigned)__shfl_xor((int)vpair, 2) << 32);
      if ((lane & 11) == 0) {   // lanes 0,4,16,20,32,36,48,52
        unsigned long long* dst =
            (unsigned long long*)(hsrow + (size_t)(mD + e) * H_ + jst);
        __hip_atomic_store(dst, vquad, __ATOMIC_RELAXED, __HIP_MEMORY_SCOPE_AGENT);
      }
    }

    // drain ONLY the h stores, then post own flag as early as possible
    asm volatile("s_waitcnt vmcnt(0)" ::: "memory");
    if (lane == 0)
      __hip_atomic_store(flags + (w << 2) + wave, (unsigned)(t + 1),
                         __ATOMIC_RELAXED, __HIP_MEMORY_SCOPE_AGENT);

    // next step's x-part (global x + LDS B + MFMA) overlaps the coming poll
    if (t + 1 < T_) computeX(t + 1);
  }
}

// ---------------- K3: out[t,b,:] = hs[t,b,:] @ W_fc^T + b_fc ----------------
__global__ void k_fc(const unsigned short* __restrict__ hs, const unsigned short* __restrict__ wfcp,
                     const float* __restrict__ bfc, float* __restrict__ out) {
  const int bm = blockIdx.x >> 2, bn = blockIdx.x & 3;
  const int tid = threadIdx.x, wave = tid >> 6, lane = tid & 63;
  const int r    = bm * 64 + wave * 16 + (lane & 15);
  const int kOff = (lane >> 4) * 8;
  const int nb   = bn * 4;   // first 16-wide n-tile index
  f32x4 acc[4];
#pragma unroll
  for (int nt = 0; nt < 4; ++nt) {
    float bv = bfc[(nb + nt) * 16 + (lane & 15)];
    acc[nt] = {bv, bv, bv, bv};
  }
  const unsigned short* arow = hs + (size_t)r * H_ + kOff;
#pragma unroll 2
  for (int kk = 0; kk < 32; ++kk) {
    bf16x8 a = *(const bf16x8*)(arow + kk * 32);
#pragma unroll
    for (int nt = 0; nt < 4; ++nt) {
      bf16x8 b = *(const bf16x8*)(wfcp + ((size_t)(kk * 16 + nb + nt) * 64 + lane) * 8);
      acc[nt] = __builtin_amdgcn_mfma_f32_16x16x32_bf16(a, b, acc[nt], 0, 0, 0);
    }
  }
  const int ro = bm * 64 + wave * 16 + (lane >> 4) * 4;
#pragma unroll
  for (int nt = 0; nt < 4; ++nt)
#pragma unroll
    for (int e = 0; e < 4; ++e)
      out[(size_t)(ro + e) * I_ + (nb + nt) * 16 + (lane & 15)] = acc[nt][e];
}

// ---------------- launcher ----------------
extern "C" void kernel_launch(void* const* d_in, const int* in_sizes, int n_in,
                              void* d_out, int out_size, void* d_ws, size_t ws_size,
                              hipStream_t stream) {
  const float* x   = (const float*)d_in[0];
  const float* h0  = (const float*)d_in[1];
  const float* c0  = (const float*)d_in[2];
  const float* Wih = (const float*)d_in[3];
  const float* Whh = (const float*)d_in[4];
  const float* bih = (const float*)d_in[5];
  const float* bhh = (const float*)d_in[6];
  const float* Wfc = (const float*)d_in[7];
  const float* bfc = (const float*)d_in[8];
  float* out = (float*)d_out;

  char* ws = (char*)d_ws;
  // ws layout (bytes): total ~95.2 MB
  unsigned short* xb    = (unsigned short*)(ws + 0);           // 16,777,216
  unsigned short* hsb   = (unsigned short*)(ws + 16777216);    // 67,108,864
  unsigned short* wpk   = (unsigned short*)(ws + 83886080);    // 10,485,760
  float*          biasp = (float*)        (ws + 94371840);     //     16,384
  unsigned short* wfcp  = (unsigned short*)(ws + 94388224);    //    524,288
  unsigned short* hbuf  = (unsigned short*)(ws + 94912512);    //    262,144
  unsigned int*   flg   = (unsigned int*)  (ws + 95174656);    //      4,096

  k_pack_x  <<<4096, 256, 0, stream>>>(x, xb);
  k_pack_w  <<<2560, 256, 0, stream>>>(Wih, Whh, bih, bhh, wpk, biasp);
  k_pack_wfc<<<128,  256, 0, stream>>>(Wfc, wfcp);
  k_init_h  <<<32,   256, 0, stream>>>(h0, hbuf, flg);
  k_lstm    <<<NWG,  256, 0, stream>>>(xb, wpk, biasp, c0, hbuf, hsb, flg);
  k_fc      <<<2048, 256, 0, stream>>>(hsb, wfcp, bfc, out);
}

// Round 11
// 4130.187 us; speedup vs baseline: 1.5182x; 1.0746x over previous
//
#include <hip/hip_runtime.h>
#include <hip/hip_bf16.h>

// Problem constants
#define B_    64
#define T_    512
#define I_    256
#define H_    1024
#define KTOT  1280          // I_ + H_
#define KSTEPS 40           // KTOT / 32
#define NWG   128           // recurrence workgroups (each owns NJ h-cols)
#define NJ    8             // h-columns per WG -> 32 gate columns
#define WPK_ELEMS (2 * KSTEPS * 64 * 8)   // 40960 bf16 per WG slice (80KB)

typedef __bf16 bf16x8 __attribute__((ext_vector_type(8)));
typedef float  f32x4  __attribute__((ext_vector_type(4)));

__device__ __forceinline__ unsigned short f2bf(float f) {
  unsigned u = __builtin_bit_cast(unsigned, f);
  u += 0x7FFFu + ((u >> 16) & 1u);       // round-to-nearest-even
  return (unsigned short)(u >> 16);
}
__device__ __forceinline__ float sigm(float x) { return 1.0f / (1.0f + __expf(-x)); }
__device__ __forceinline__ float tanh_fast(float x) {
  float ax = fabsf(x);
  float e  = __expf(-2.0f * ax);          // in (0,1], no overflow
  float t  = (1.0f - e) / (1.0f + e);
  return x < 0.0f ? -t : t;
}

// ---------------- K0: x [B,T,I] f32 -> xb [T,B,I] bf16 ----------------
__global__ void k_pack_x(const float* __restrict__ x, unsigned short* __restrict__ xb) {
  int idx = blockIdx.x * blockDim.x + threadIdx.x;   // over B*T*I/8 = 1,048,576
  int ic = idx & 31;             // I/8 = 32
  int t  = (idx >> 5) & 511;     // T = 512
  int b  = idx >> 14;            // B = 64
  const float* src = x + ((size_t)b * T_ + t) * I_ + ic * 8;
  float4 f0 = *(const float4*)src;
  float4 f1 = *(const float4*)(src + 4);
  unsigned short o[8] = {f2bf(f0.x), f2bf(f0.y), f2bf(f0.z), f2bf(f0.w),
                         f2bf(f1.x), f2bf(f1.y), f2bf(f1.z), f2bf(f1.w)};
  *(uint4*)(xb + ((size_t)t * B_ + b) * I_ + ic * 8) = *(uint4*)o;
}

// ---------------- K1a: pack W_ih|W_hh into per-WG B-fragment layout ----------------
// layout: [w][nt][kk][lane][e], value = W[gate*H + w*NJ + (n&7)][k] with
// n = lane&15 (n<8 -> gate nt*2, n>=8 -> gate nt*2+1), k = kk*32 + (lane>>4)*8 + e
__global__ void k_pack_w(const float* __restrict__ Wih, const float* __restrict__ Whh,
                         const float* __restrict__ bih, const float* __restrict__ bhh,
                         unsigned short* __restrict__ wpack, float* __restrict__ biasp) {
  int f = blockIdx.x * blockDim.x + threadIdx.x;     // 128*2*40*64 = 655,360
  int l  = f & 63;
  int q  = f >> 6;
  int kk = q % KSTEPS;
  int q2 = q / KSTEPS;
  int nt = q2 & 1;
  int w  = q2 >> 1;
  int n  = l & 15;
  int g  = nt * 2 + (n >> 3);
  int r  = g * H_ + w * NJ + (n & 7);
  int k0 = kk * 32 + (l >> 4) * 8;
  unsigned short o[8];
#pragma unroll
  for (int e = 0; e < 8; ++e) {
    int k = k0 + e;
    float v = (k < I_) ? Wih[(size_t)r * I_ + k] : Whh[(size_t)r * H_ + (k - I_)];
    o[e] = f2bf(v);
  }
  *(uint4*)(wpack + (size_t)f * 8) = *(uint4*)o;
  if (kk == 0 && (l >> 4) == 0) biasp[w * 32 + nt * 16 + n] = bih[r] + bhh[r];
}

// ---------------- K1b: pack W_fc [I,H] -> fragment layout [kk][nt][lane][e] ----------------
__global__ void k_pack_wfc(const float* __restrict__ Wfc, unsigned short* __restrict__ wfcp) {
  int f = blockIdx.x * blockDim.x + threadIdx.x;     // 32*16*64 = 32768
  int l  = f & 63;
  int nt = (f >> 6) & 15;
  int kk = f >> 10;
  int n  = nt * 16 + (l & 15);
  int k0 = kk * 32 + (l >> 4) * 8;
  unsigned short o[8];
#pragma unroll
  for (int e = 0; e < 8; ++e) o[e] = f2bf(Wfc[(size_t)n * H_ + k0 + e]);
  *(uint4*)(wfcp + (size_t)f * 8) = *(uint4*)o;
}

// ---------------- K1c: h0 -> bf16 hbuf; zero flags+epoch ----------------
__global__ void k_init_h(const float* __restrict__ h0, unsigned short* __restrict__ hbuf,
                         unsigned int* __restrict__ flags) {
  int idx = blockIdx.x * blockDim.x + threadIdx.x;   // B*H/8 = 8192
  const float* s = h0 + (size_t)idx * 8;
  unsigned short o[8];
#pragma unroll
  for (int e = 0; e < 8; ++e) o[e] = f2bf(s[e]);
  *(uint4*)(hbuf + (size_t)idx * 8) = *(uint4*)o;
  if (idx < 1024) flags[idx] = 0;   // covers 512 flags + 128 epoch words
}

// 32 parallel h-fragment loads (one address, imm offsets 0..1984), single wait.
#define HLOAD32(P)                                                          \
  asm volatile(                                                             \
    "global_load_dwordx4 %0,  %32, off\n\t"                                 \
    "global_load_dwordx4 %1,  %32, off offset:64\n\t"                       \
    "global_load_dwordx4 %2,  %32, off offset:128\n\t"                      \
    "global_load_dwordx4 %3,  %32, off offset:192\n\t"                      \
    "global_load_dwordx4 %4,  %32, off offset:256\n\t"                      \
    "global_load_dwordx4 %5,  %32, off offset:320\n\t"                      \
    "global_load_dwordx4 %6,  %32, off offset:384\n\t"                      \
    "global_load_dwordx4 %7,  %32, off offset:448\n\t"                      \
    "global_load_dwordx4 %8,  %32, off offset:512\n\t"                      \
    "global_load_dwordx4 %9,  %32, off offset:576\n\t"                      \
    "global_load_dwordx4 %10, %32, off offset:640\n\t"                      \
    "global_load_dwordx4 %11, %32, off offset:704\n\t"                      \
    "global_load_dwordx4 %12, %32, off offset:768\n\t"                      \
    "global_load_dwordx4 %13, %32, off offset:832\n\t"                      \
    "global_load_dwordx4 %14, %32, off offset:896\n\t"                      \
    "global_load_dwordx4 %15, %32, off offset:960\n\t"                      \
    "global_load_dwordx4 %16, %32, off offset:1024\n\t"                     \
    "global_load_dwordx4 %17, %32, off offset:1088\n\t"                     \
    "global_load_dwordx4 %18, %32, off offset:1152\n\t"                     \
    "global_load_dwordx4 %19, %32, off offset:1216\n\t"                     \
    "global_load_dwordx4 %20, %32, off offset:1280\n\t"                     \
    "global_load_dwordx4 %21, %32, off offset:1344\n\t"                     \
    "global_load_dwordx4 %22, %32, off offset:1408\n\t"                     \
    "global_load_dwordx4 %23, %32, off offset:1472\n\t"                     \
    "global_load_dwordx4 %24, %32, off offset:1536\n\t"                     \
    "global_load_dwordx4 %25, %32, off offset:1600\n\t"                     \
    "global_load_dwordx4 %26, %32, off offset:1664\n\t"                     \
    "global_load_dwordx4 %27, %32, off offset:1728\n\t"                     \
    "global_load_dwordx4 %28, %32, off offset:1792\n\t"                     \
    "global_load_dwordx4 %29, %32, off offset:1856\n\t"                     \
    "global_load_dwordx4 %30, %32, off offset:1920\n\t"                     \
    "global_load_dwordx4 %31, %32, off offset:1984\n\t"                     \
    "s_waitcnt vmcnt(0)"                                                    \
    : "=&v"(h00), "=&v"(h01), "=&v"(h02), "=&v"(h03), "=&v"(h04),           \
      "=&v"(h05), "=&v"(h06), "=&v"(h07), "=&v"(h08), "=&v"(h09),           \
      "=&v"(h10), "=&v"(h11), "=&v"(h12), "=&v"(h13), "=&v"(h14),           \
      "=&v"(h15), "=&v"(h16), "=&v"(h17), "=&v"(h18), "=&v"(h19),           \
      "=&v"(h20), "=&v"(h21), "=&v"(h22), "=&v"(h23), "=&v"(h24),           \
      "=&v"(h25), "=&v"(h26), "=&v"(h27), "=&v"(h28), "=&v"(h29),           \
      "=&v"(h30), "=&v"(h31)                                                \
    : "v"(P) : "memory")

// one K-slice: 2 MFMAs, B operands from the register-resident W (wh0/wh1)
#define STEP_H(HF, I)                                                               \
  acc0 = __builtin_amdgcn_mfma_f32_16x16x32_bf16(__builtin_bit_cast(bf16x8, HF),    \
                                                 wh0[I], acc0, 0, 0, 0);            \
  acc1 = __builtin_amdgcn_mfma_f32_16x16x32_bf16(__builtin_bit_cast(bf16x8, HF),    \
                                                 wh1[I], acc1, 0, 0, 0);

// ---------------- K2: persistent LSTM recurrence ----------------
// 128 producer WGs x 256 threads + 1 AGGREGATOR WG (blockIdx == 128).
// Producers: identical to R10 (register-resident h-part W, asm h-load block,
// sc1 write-through h stores, early per-wave flag post) EXCEPT the wait:
// instead of every wave re-fetching all 512 flags (O(waves x flags) MALL
// contention, ~4 TB/s on 32 lines), each wave polls ONE replicated epoch
// line (64 B, wave-uniform address). The aggregator WG's 4 waves each poll
// one quarter of the 512 flags and post per-quarter epoch words, replicated
// into 8 cache lines (consumers pick line w&7).
// flags layout: [0..511] per-wave flags; [512..639] epoch: line r (r=0..7)
// at u32 index 512 + r*16, words q=0..3 hold quarter-q epoch.
__global__ void __launch_bounds__(256, 1) k_lstm(
    const unsigned short* __restrict__ xb, const unsigned short* __restrict__ wpack,
    const float* __restrict__ biasp, const float* __restrict__ c0,
    const unsigned short* __restrict__ hbuf, unsigned short* __restrict__ hs,
    unsigned int* __restrict__ flags) {
  __shared__ unsigned short xlds[2 * 8 * 64 * 8];   // 16 KB: x-part W only
  const int w    = blockIdx.x;
  const int tid  = threadIdx.x;
  const int wave = tid >> 6, lane = tid & 63;

  // ---------------- aggregator WG ----------------
  if (w == NWG) {
    // wave q owns flags[q*128 .. q*128+127]: one dwordx2 per lane
    const unsigned long long* fp =
        (const unsigned long long*)flags + (wave << 6) + lane;
    unsigned* ep = flags + 512;
    for (int t = 1; t < T_; ++t) {
      const unsigned target = (unsigned)t;
      int guard = 0;
      for (;;) {
        unsigned long long v;
        asm volatile("global_load_dwordx2 %0, %1, off sc1\n\ts_waitcnt vmcnt(0)"
                     : "=&v"(v) : "v"(fp) : "memory");
        if (__all(((unsigned)v >= target) && ((unsigned)(v >> 32) >= target))) break;
        if (++guard > (1 << 22)) break;   // safety: never hard-hang
      }
      if (lane < 8)   // replicate this quarter's epoch into 8 lines
        __hip_atomic_store(ep + lane * 16 + wave, target,
                           __ATOMIC_RELAXED, __HIP_MEMORY_SCOPE_AGENT);
    }
    return;
  }

  const uint4* wp4 = (const uint4*)wpack + (size_t)w * (2 * KSTEPS * 64);

  { // x-part W (slots 0..7, both tiles) into LDS
    uint4* xl4 = (uint4*)xlds;
    for (int i = tid; i < 1024; i += 256) {
      int nt = i >> 9, kk = (i >> 6) & 7, l = i & 63;
      xl4[i] = wp4[(size_t)(nt * KSTEPS + kk) * 64 + l];
    }
  }

  // h-part W (slots 8..39, both tiles) into registers: 256 regs/lane
  bf16x8 wh0[32], wh1[32];
#pragma unroll
  for (int i = 0; i < 32; ++i) {
    wh0[i] = __builtin_bit_cast(bf16x8, wp4[(size_t)(8 + i) * 64 + lane]);
    wh1[i] = __builtin_bit_cast(bf16x8, wp4[(size_t)(KSTEPS + 8 + i) * 64 + lane]);
  }

  const int mA   = wave * 16 + (lane & 15);    // A-fragment row = batch index
  const int kOff = (lane >> 4) * 8;            // A-fragment k offset within 32
  const int mD   = wave * 16 + (lane >> 4) * 4;// D-fragment row base
  const int jst  = w * NJ + (lane & 7);        // owned h-column

  const float bias0 = biasp[w * 32 + (lane & 15)];
  const float bias1 = biasp[w * 32 + 16 + (lane & 15)];
  float creg[4];
#pragma unroll
  for (int e = 0; e < 4; ++e) creg[e] = c0[(size_t)(mD + e) * H_ + jst];

  __syncthreads();   // LDS x-W ready

  f32x4 xacc0, xacc1;
  // x-part of step t: global x loads + LDS B reads + 16 MFMA, all in the
  // post-flag shadow (never on the inter-step critical path)
  auto computeX = [&](int t) {
    xacc0 = f32x4{bias0, bias0, bias0, bias0};
    xacc1 = f32x4{bias1, bias1, bias1, bias1};
    const unsigned short* xrow = xb + ((size_t)t * B_ + mA) * I_ + kOff;
#pragma unroll
    for (int kk = 0; kk < 8; ++kk) {
      bf16x8 a  = *(const bf16x8*)(xrow + kk * 32);
      bf16x8 b0 = *(const bf16x8*)(xlds + ((size_t)(kk) * 64 + lane) * 8);
      bf16x8 b1 = *(const bf16x8*)(xlds + ((size_t)(8 + kk) * 64 + lane) * 8);
      xacc0 = __builtin_amdgcn_mfma_f32_16x16x32_bf16(a, b0, xacc0, 0, 0, 0);
      xacc1 = __builtin_amdgcn_mfma_f32_16x16x32_bf16(a, b1, xacc1, 0, 0, 0);
    }
  };
  computeX(0);

  const uint4* ep = (const uint4*)(flags + 512 + (w & 7) * 16);  // my epoch line

  for (int t = 0; t < T_; ++t) {
    // ---- wait: poll ONE replicated epoch line (wave-uniform 64B fetch) ----
    if (t > 0) {
      const unsigned target = (unsigned)t;
      int guard = 0;
      for (;;) {
        uint4 v;
        asm volatile("global_load_dwordx4 %0, %1, off sc1\n\ts_waitcnt vmcnt(0)"
                     : "=&v"(v) : "v"(ep) : "memory");
        if (v.x >= target && v.y >= target && v.z >= target && v.w >= target) break;
        if (++guard > (1 << 20)) break;   // safety: never hard-hang
      }
      asm volatile("" ::: "memory");
    }

    // ---- 32 h fragments, one parallel load block ----
    const unsigned short* hprev = (t == 0) ? hbuf : hs + (size_t)(t - 1) * (B_ * H_);
    const unsigned short* hrow = hprev + (size_t)mA * H_ + kOff;
    uint4 h00,h01,h02,h03,h04,h05,h06,h07,h08,h09,h10,h11,h12,h13,h14,h15,
          h16,h17,h18,h19,h20,h21,h22,h23,h24,h25,h26,h27,h28,h29,h30,h31;
    HLOAD32(hrow);

    // ---- 64 MFMAs, all operands in registers ----
    f32x4 acc0 = xacc0, acc1 = xacc1;
    STEP_H(h00,  0) STEP_H(h01,  1) STEP_H(h02,  2) STEP_H(h03,  3)
    STEP_H(h04,  4) STEP_H(h05,  5) STEP_H(h06,  6) STEP_H(h07,  7)
    STEP_H(h08,  8) STEP_H(h09,  9) STEP_H(h10, 10) STEP_H(h11, 11)
    STEP_H(h12, 12) STEP_H(h13, 13) STEP_H(h14, 14) STEP_H(h15, 15)
    STEP_H(h16, 16) STEP_H(h17, 17) STEP_H(h18, 18) STEP_H(h19, 19)
    STEP_H(h20, 20) STEP_H(h21, 21) STEP_H(h22, 22) STEP_H(h23, 23)
    STEP_H(h24, 24) STEP_H(h25, 25) STEP_H(h26, 26) STEP_H(h27, 27)
    STEP_H(h28, 28) STEP_H(h29, 29) STEP_H(h30, 30) STEP_H(h31, 31)

    // gates: acc0 = [i|f], acc1 = [g|o]; f/o live in lane^8
    unsigned short hbits[4];
#pragma unroll
    for (int e = 0; e < 4; ++e) {
      float ip  = acc0[e], gp = acc1[e];
      float fp_ = __shfl_xor(ip, 8);
      float op_ = __shfl_xor(gp, 8);
      float ig = sigm(ip), fg = sigm(fp_), gg = tanh_fast(gp), og = sigm(op_);
      float cn = fg * creg[e] + ig * gg;
      creg[e] = cn;
      hbits[e] = f2bf(og * tanh_fast(cn));
    }

    // store h_t: gather 4 adjacent cols into one 8B sc1 store
    unsigned short* hsrow = hs + (size_t)t * (B_ * H_);
#pragma unroll
    for (int e = 0; e < 4; ++e) {
      unsigned vpair = (unsigned)hbits[e] | ((unsigned)__shfl_xor((int)hbits[e], 1) << 16);
      unsigned long long vquad =
          (unsigned long long)vpair |
          ((unsigned long long)(unsigned)__shfl_xor((int)vpair, 2) << 32);
      if ((lane & 11) == 0) {   // lanes 0,4,16,20,32,36,48,52
        unsigned long long* dst =
            (unsigned long long*)(hsrow + (size_t)(mD + e) * H_ + jst);
        __hip_atomic_store(dst, vquad, __ATOMIC_RELAXED, __HIP_MEMORY_SCOPE_AGENT);
      }
    }

    // drain ONLY the h stores, then post own flag as early as possible
    asm volatile("s_waitcnt vmcnt(0)" ::: "memory");
    if (lane == 0)
      __hip_atomic_store(flags + (w << 2) + wave, (unsigned)(t + 1),
                         __ATOMIC_RELAXED, __HIP_MEMORY_SCOPE_AGENT);

    // next step's x-part (global x + LDS B + MFMA) overlaps the coming poll
    if (t + 1 < T_) computeX(t + 1);
  }
}

// ---------------- K3: out[t,b,:] = hs[t,b,:] @ W_fc^T + b_fc ----------------
__global__ void k_fc(const unsigned short* __restrict__ hs, const unsigned short* __restrict__ wfcp,
                     const float* __restrict__ bfc, float* __restrict__ out) {
  const int bm = blockIdx.x >> 2, bn = blockIdx.x & 3;
  const int tid = threadIdx.x, wave = tid >> 6, lane = tid & 63;
  const int r    = bm * 64 + wave * 16 + (lane & 15);
  const int kOff = (lane >> 4) * 8;
  const int nb   = bn * 4;   // first 16-wide n-tile index
  f32x4 acc[4];
#pragma unroll
  for (int nt = 0; nt < 4; ++nt) {
    float bv = bfc[(nb + nt) * 16 + (lane & 15)];
    acc[nt] = {bv, bv, bv, bv};
  }
  const unsigned short* arow = hs + (size_t)r * H_ + kOff;
#pragma unroll 2
  for (int kk = 0; kk < 32; ++kk) {
    bf16x8 a = *(const bf16x8*)(arow + kk * 32);
#pragma unroll
    for (int nt = 0; nt < 4; ++nt) {
      bf16x8 b = *(const bf16x8*)(wfcp + ((size_t)(kk * 16 + nb + nt) * 64 + lane) * 8);
      acc[nt] = __builtin_amdgcn_mfma_f32_16x16x32_bf16(a, b, acc[nt], 0, 0, 0);
    }
  }
  const int ro = bm * 64 + wave * 16 + (lane >> 4) * 4;
#pragma unroll
  for (int nt = 0; nt < 4; ++nt)
#pragma unroll
    for (int e = 0; e < 4; ++e)
      out[(size_t)(ro + e) * I_ + (nb + nt) * 16 + (lane & 15)] = acc[nt][e];
}

// ---------------- launcher ----------------
extern "C" void kernel_launch(void* const* d_in, const int* in_sizes, int n_in,
                              void* d_out, int out_size, void* d_ws, size_t ws_size,
                              hipStream_t stream) {
  const float* x   = (const float*)d_in[0];
  const float* h0  = (const float*)d_in[1];
  const float* c0  = (const float*)d_in[2];
  const float* Wih = (const float*)d_in[3];
  const float* Whh = (const float*)d_in[4];
  const float* bih = (const float*)d_in[5];
  const float* bhh = (const float*)d_in[6];
  const float* Wfc = (const float*)d_in[7];
  const float* bfc = (const float*)d_in[8];
  float* out = (float*)d_out;

  char* ws = (char*)d_ws;
  // ws layout (bytes): total ~95.2 MB
  unsigned short* xb    = (unsigned short*)(ws + 0);           // 16,777,216
  unsigned short* hsb   = (unsigned short*)(ws + 16777216);    // 67,108,864
  unsigned short* wpk   = (unsigned short*)(ws + 83886080);    // 10,485,760
  float*          biasp = (float*)        (ws + 94371840);     //     16,384
  unsigned short* wfcp  = (unsigned short*)(ws + 94388224);    //    524,288
  unsigned short* hbuf  = (unsigned short*)(ws + 94912512);    //    262,144
  unsigned int*   flg   = (unsigned int*)  (ws + 95174656);    //      4,096

  k_pack_x  <<<4096, 256, 0, stream>>>(x, xb);
  k_pack_w  <<<2560, 256, 0, stream>>>(Wih, Whh, bih, bhh, wpk, biasp);
  k_pack_wfc<<<128,  256, 0, stream>>>(Wfc, wfcp);
  k_init_h  <<<32,   256, 0, stream>>>(h0, hbuf, flg);
  k_lstm    <<<NWG + 1, 256, 0, stream>>>(xb, wpk, biasp, c0, hbuf, hsb, flg);
  k_fc      <<<2048, 256, 0, stream>>>(hsb, wfcp, bfc, out);
}

// Round 13
// 2372.673 us; speedup vs baseline: 2.6428x; 1.7407x over previous
//
#include <hip/hip_runtime.h>
#include <hip/hip_bf16.h>

// Problem constants
#define B_    64
#define T_    512
#define I_    256
#define H_    1024
#define KSTEPS 40          // (I_+H_)/32
#define NGRP  8            // batch groups (logical; round-robin => 1 XCD each)
#define BG    8            // batch rows per group
#define RPG   32           // WGs (ranks) per group
#define NWG   256          // total recurrence WGs
#define HROWB 2064         // padded hlds row stride in bytes (2048 + 16)

typedef __bf16 bf16x8 __attribute__((ext_vector_type(8)));
typedef float  f32x4  __attribute__((ext_vector_type(4)));

__device__ __forceinline__ unsigned short f2bf(float f) {
  unsigned u = __builtin_bit_cast(unsigned, f);
  u += 0x7FFFu + ((u >> 16) & 1u);       // round-to-nearest-even
  return (unsigned short)(u >> 16);
}
__device__ __forceinline__ float sigm(float x) { return 1.0f / (1.0f + __expf(-x)); }
__device__ __forceinline__ float tanh_fast(float x) {
  float ax = fabsf(x);
  float e  = __expf(-2.0f * ax);
  float t  = (1.0f - e) / (1.0f + e);
  return x < 0.0f ? -t : t;
}

// ---------------- K0: x [B,T,I] f32 -> xb [T,B,I] bf16 ----------------
__global__ void k_pack_x(const float* __restrict__ x, unsigned short* __restrict__ xb) {
  int idx = blockIdx.x * blockDim.x + threadIdx.x;   // B*T*I/8 = 1,048,576
  int ic = idx & 31;
  int t  = (idx >> 5) & 511;
  int b  = idx >> 14;
  const float* src = x + ((size_t)b * T_ + t) * I_ + ic * 8;
  float4 f0 = *(const float4*)src;
  float4 f1 = *(const float4*)(src + 4);
  unsigned short o[8] = {f2bf(f0.x), f2bf(f0.y), f2bf(f0.z), f2bf(f0.w),
                         f2bf(f1.x), f2bf(f1.y), f2bf(f1.z), f2bf(f1.w)};
  *(uint4*)(xb + ((size_t)t * B_ + b) * I_ + ic * 8) = *(uint4*)o;
}

// ---------------- K1a: pack W into per-(rank,wave) B-fragment layout ----------------
// wave v of rank r owns gate tile: gate = v>>1, cols r*32 + (v&1)*16 + (lane&15).
// layout: [((r*8+v)*40 + kk)*64 + lane] (16B frag), k = kk*32 + (lane>>4)*8 + e.
__global__ void k_pack_w(const float* __restrict__ Wih, const float* __restrict__ Whh,
                         const float* __restrict__ bih, const float* __restrict__ bhh,
                         unsigned short* __restrict__ wpack, float* __restrict__ biasp) {
  int f = blockIdx.x * blockDim.x + threadIdx.x;     // 32*8*40*64 = 655,360
  int l  = f & 63;
  int q  = f >> 6;
  int kk = q % KSTEPS;
  int q2 = q / KSTEPS;
  int v  = q2 & 7;
  int r  = q2 >> 3;
  int gate = v >> 1;
  int col  = r * 32 + (v & 1) * 16 + (l & 15);
  int grow = gate * H_ + col;
  int k0 = kk * 32 + (l >> 4) * 8;
  unsigned short o[8];
#pragma unroll
  for (int e = 0; e < 8; ++e) {
    int k = k0 + e;
    float val = (k < I_) ? Wih[(size_t)grow * I_ + k] : Whh[(size_t)grow * H_ + (k - I_)];
    o[e] = f2bf(val);
  }
  *(uint4*)(wpack + (size_t)f * 8) = *(uint4*)o;
  if (kk == 0 && (l >> 4) == 0)
    biasp[(r * 8 + v) * 16 + (l & 15)] = bih[grow] + bhh[grow];
}

// ---------------- K1b: pack W_fc [I,H] -> fragment layout ----------------
__global__ void k_pack_wfc(const float* __restrict__ Wfc, unsigned short* __restrict__ wfcp) {
  int f = blockIdx.x * blockDim.x + threadIdx.x;     // 32768
  int l  = f & 63;
  int nt = (f >> 6) & 15;
  int kk = f >> 10;
  int n  = nt * 16 + (l & 15);
  int k0 = kk * 32 + (l >> 4) * 8;
  unsigned short o[8];
#pragma unroll
  for (int e = 0; e < 8; ++e) o[e] = f2bf(Wfc[(size_t)n * H_ + k0 + e]);
  *(uint4*)(wfcp + (size_t)f * 8) = *(uint4*)o;
}

// ---------------- K1c: h0 -> bf16 hbuf [B][H]; zero flags ----------------
__global__ void k_init_h(const float* __restrict__ h0, unsigned short* __restrict__ hbuf,
                         unsigned int* __restrict__ flags) {
  int idx = blockIdx.x * blockDim.x + threadIdx.x;   // 8192
  const float* s = h0 + (size_t)idx * 8;
  unsigned short o[8];
#pragma unroll
  for (int e = 0; e < 8; ++e) o[e] = f2bf(s[e]);
  *(uint4*)(hbuf + (size_t)idx * 8) = *(uint4*)o;
  if (idx < 1024) flags[idx] = 0;
}

// ---------------- K2: grouped persistent LSTM recurrence ----------------
// 256 WGs x 512 threads. LOGICAL groups: g = blockIdx&7 (round-robin => same
// XCD, heuristic only), rank r = blockIdx>>3. Group g owns batch rows
// [g*8, g*8+8); rank r owns h-cols [r*32, r*32+32). Wave v computes gate tile
// (gate=v>>1, half=v&1) with W_hh in REGISTERS (128 VGPR/lane).
// Coherence (placement-independent, the R4-R11-validated protocol):
//   h exchange streams into hs[t] (unique addr/step -> no stale lines) via
//   sc1 write-through stores; consumers use plain cached loads. Flags stored
//   agent-scope after a vmcnt(0)-drained barrier; polled with sc1 loads.
__global__ void __launch_bounds__(512, 2) k_lstm(
    const unsigned short* __restrict__ xb, const unsigned short* __restrict__ wpack,
    const float* __restrict__ biasp, const float* __restrict__ c0,
    const unsigned short* __restrict__ hbuf, unsigned short* __restrict__ hs,
    unsigned int* __restrict__ flags) {
  __shared__ unsigned short hlds[8 * HROWB / 2];   // 16.5 KB staged h (padded rows)
  __shared__ f32x4 pacc[8][64];                    // 8 KB gate partials
  __shared__ uint4 xlds[8 * 8 * 64];               // 64 KB x-part W
  const int tid  = threadIdx.x;
  const int wave = tid >> 6, lane = tid & 63;
  const int g = blockIdx.x & 7, r = blockIdx.x >> 3;

  const uint4* wp4 = (const uint4*)wpack;
  { // x-part W (kk 0..7, all 8 tiles of this rank) into LDS
    for (int i = tid; i < 4096; i += 512) {
      int v = i >> 9, kk = (i >> 6) & 7, l = i & 63;
      xlds[i] = wp4[(size_t)((r * 8 + v) * KSTEPS + kk) * 64 + l];
    }
  }
  // h-part W (kk 8..39) for MY gate tile into registers: 128 VGPRs
  bf16x8 wr[32];
#pragma unroll
  for (int j = 0; j < 32; ++j)
    wr[j] = __builtin_bit_cast(bf16x8, wp4[(size_t)((r * 8 + wave) * KSTEPS + 8 + j) * 64 + lane]);

  const int row   = (lane & 15) & 7;           // batch row within group (2x dup in M)
  const int koffb = (lane >> 4) * 16;          // A-frag k byte offset
  const int hbase = row * HROWB + koffb;       // per-lane LDS h base
  const float bv = biasp[(r * 8 + wave) * 16 + (lane & 15)];
  float creg = 0.f;
  if (lane < 32)
    creg = c0[(size_t)(g * BG + (lane & 7)) * H_ + r * 32 + wave * 4 + (lane >> 3)];

  __syncthreads();   // xlds ready

  f32x4 xacc;
  auto computeX = [&](int t) {   // post-flag shadow: x loads + LDS W + 8 MFMA
    xacc = f32x4{bv, bv, bv, bv};
    const unsigned short* xrow = xb + ((size_t)t * B_ + g * BG + row) * I_ + (lane >> 4) * 8;
#pragma unroll
    for (int kk = 0; kk < 8; ++kk) {
      bf16x8 a = *(const bf16x8*)(xrow + kk * 32);
      bf16x8 b = __builtin_bit_cast(bf16x8, xlds[(wave * 8 + kk) * 64 + lane]);
      xacc = __builtin_amdgcn_mfma_f32_16x16x32_bf16(a, b, xacc, 0, 0, 0);
    }
  };
  computeX(0);

  for (int t = 0; t < T_; ++t) {
    // ---- wait: wave0 polls this group's 32 rank-flags (sc1 = MALL-fresh) ----
    if (t > 0) {
      if (wave == 0) {
        const unsigned* fp = flags + g * 32 + (lane & 31);
        const unsigned target = (unsigned)t;
        int guard = 0;
        for (;;) {
          unsigned fv;
          asm volatile("global_load_dword %0, %1, off sc1\n\ts_waitcnt vmcnt(0)"
                       : "=&v"(fv) : "v"(fp) : "memory");
          if (__all(fv >= target)) break;
          if (++guard > (1 << 20)) break;   // safety: never hard-hang
        }
      }
      __syncthreads();   // A: release all waves; orders poll before h loads
    }

    // ---- stage h_prev (group rows only, 16 KB) into LDS: wave v = row v ----
    {
      const unsigned short* src =
          (t == 0) ? hbuf + (size_t)(g * BG + wave) * H_ + lane * 8
                   : hs + ((size_t)(t - 1) * B_ + g * BG + wave) * H_ + lane * 8;
      uint4 a0 = *(const uint4*)src;
      uint4 a1 = *(const uint4*)(src + 512);
      char* dst = (char*)hlds + wave * HROWB + lane * 16;
      *(uint4*)dst = a0;
      *(uint4*)(dst + 1024) = a1;
    }
    __syncthreads();   // B: hlds ready

    // ---- 32 MFMAs (W in regs, h from LDS), 2 independent chains ----
    f32x4 accA = xacc, accB = {0.f, 0.f, 0.f, 0.f};
    const char* hb = (const char*)hlds + hbase;
#pragma unroll
    for (int j = 0; j < 32; j += 2) {
      bf16x8 h0f = *(const bf16x8*)(hb + j * 64);
      bf16x8 h1f = *(const bf16x8*)(hb + j * 64 + 64);
      accA = __builtin_amdgcn_mfma_f32_16x16x32_bf16(h0f, wr[j], accA, 0, 0, 0);
      accB = __builtin_amdgcn_mfma_f32_16x16x32_bf16(h1f, wr[j + 1], accB, 0, 0, 0);
    }
    pacc[wave][lane] = accA + accB;
    __syncthreads();   // C: all gate tiles in LDS

    // ---- combine i/f/g/o (cross-wave via pacc) + gate math; c in regs ----
    unsigned hbp = 0;
    if (lane < 32) {
      const int rw   = lane & 7;               // batch row
      const int jj   = wave * 4 + (lane >> 3); // col within rank's 32
      const int half = jj >> 4;
      const int lp   = ((rw & 4) << 2) | (jj & 15);
      const int e    = rw & 3;
      const float* pf = (const float*)pacc;
      float gi = pf[((0 * 2 + half) * 64 + lp) * 4 + e];
      float gf = pf[((1 * 2 + half) * 64 + lp) * 4 + e];
      float gg = pf[((2 * 2 + half) * 64 + lp) * 4 + e];
      float go = pf[((3 * 2 + half) * 64 + lp) * 4 + e];
      float ig = sigm(gi), fg = sigm(gf), g2 = tanh_fast(gg), og = sigm(go);
      float cn = fg * creg + ig * g2;
      creg = cn;
      hbp = f2bf(og * tanh_fast(cn));
    }
    // gather 4 cols (lanes rw, rw+8, rw+16, rw+24) into lanes 0..7, 8B sc1 store
    {
      int base = lane & 7;
      unsigned lo = ((unsigned)__shfl((int)hbp, base) & 0xFFFFu) |
                    ((unsigned)__shfl((int)hbp, base + 8) << 16);
      unsigned hi = ((unsigned)__shfl((int)hbp, base + 16) & 0xFFFFu) |
                    ((unsigned)__shfl((int)hbp, base + 24) << 16);
      if (lane < 8) {
        unsigned long long q = (unsigned long long)lo | ((unsigned long long)hi << 32);
        unsigned long long* dst = (unsigned long long*)
            (hs + ((size_t)t * B_ + g * BG + lane) * H_ + (size_t)r * 32 + wave * 4);
        __hip_atomic_store(dst, q, __ATOMIC_RELAXED, __HIP_MEMORY_SCOPE_AGENT);
      }
    }

    asm volatile("s_waitcnt vmcnt(0)" ::: "memory");   // own stores drained
    __syncthreads();   // D: ALL waves' stores drained
    if (tid == 0)
      __hip_atomic_store(flags + g * 32 + r, (unsigned)(t + 1),
                         __ATOMIC_RELAXED, __HIP_MEMORY_SCOPE_AGENT);

    // next step's x-part overlaps the coming poll window
    if (t + 1 < T_) computeX(t + 1);
  }
}

// ---------------- K3: out[t,b,:] = hs[t,b,:] @ W_fc^T + b_fc ----------------
__global__ void k_fc(const unsigned short* __restrict__ hs, const unsigned short* __restrict__ wfcp,
                     const float* __restrict__ bfc, float* __restrict__ out) {
  const int bm = blockIdx.x >> 2, bn = blockIdx.x & 3;
  const int tid = threadIdx.x, wave = tid >> 6, lane = tid & 63;
  const int r    = bm * 64 + wave * 16 + (lane & 15);
  const int kOff = (lane >> 4) * 8;
  const int nb   = bn * 4;
  f32x4 acc[4];
#pragma unroll
  for (int nt = 0; nt < 4; ++nt) {
    float bvv = bfc[(nb + nt) * 16 + (lane & 15)];
    acc[nt] = {bvv, bvv, bvv, bvv};
  }
  const unsigned short* arow = hs + (size_t)r * H_ + kOff;
#pragma unroll 2
  for (int kk = 0; kk < 32; ++kk) {
    bf16x8 a = *(const bf16x8*)(arow + kk * 32);
#pragma unroll
    for (int nt = 0; nt < 4; ++nt) {
      bf16x8 b = *(const bf16x8*)(wfcp + ((size_t)(kk * 16 + nb + nt) * 64 + lane) * 8);
      acc[nt] = __builtin_amdgcn_mfma_f32_16x16x32_bf16(a, b, acc[nt], 0, 0, 0);
    }
  }
  const int ro = bm * 64 + wave * 16 + (lane >> 4) * 4;
#pragma unroll
  for (int nt = 0; nt < 4; ++nt)
#pragma unroll
    for (int e = 0; e < 4; ++e)
      out[(size_t)(ro + e) * I_ + (nb + nt) * 16 + (lane & 15)] = acc[nt][e];
}

// ---------------- launcher ----------------
extern "C" void kernel_launch(void* const* d_in, const int* in_sizes, int n_in,
                              void* d_out, int out_size, void* d_ws, size_t ws_size,
                              hipStream_t stream) {
  const float* x   = (const float*)d_in[0];
  const float* h0  = (const float*)d_in[1];
  const float* c0  = (const float*)d_in[2];
  const float* Wih = (const float*)d_in[3];
  const float* Whh = (const float*)d_in[4];
  const float* bih = (const float*)d_in[5];
  const float* bhh = (const float*)d_in[6];
  const float* Wfc = (const float*)d_in[7];
  const float* bfc = (const float*)d_in[8];
  float* out = (float*)d_out;

  char* ws = (char*)d_ws;
  unsigned short* xb    = (unsigned short*)(ws + 0);           // 16,777,216
  unsigned short* hsb   = (unsigned short*)(ws + 16777216);    // 67,108,864
  unsigned short* wpk   = (unsigned short*)(ws + 83886080);    // 10,485,760
  float*          biasp = (float*)        (ws + 94371840);     //     16,384
  unsigned short* wfcp  = (unsigned short*)(ws + 94388224);    //    524,288
  unsigned short* hbuf  = (unsigned short*)(ws + 94912512);    //    262,144
  unsigned int*   flg   = (unsigned int*)  (ws + 95174656);    //      4,096

  k_pack_x  <<<4096, 256, 0, stream>>>(x, xb);
  k_pack_w  <<<2560, 256, 0, stream>>>(Wih, Whh, bih, bhh, wpk, biasp);
  k_pack_wfc<<<128,  256, 0, stream>>>(Wfc, wfcp);
  k_init_h  <<<32,   256, 0, stream>>>(h0, hbuf, flg);
  k_lstm    <<<NWG,  512, 0, stream>>>(xb, wpk, biasp, c0, hbuf, hsb, flg);
  k_fc      <<<2048, 256, 0, stream>>>(hsb, wfcp, bfc, out);
}